// Round 10
// baseline (961.562 us; speedup 1.0000x reference)
//
#include <hip/hip_runtime.h>
#include <hip/hip_bf16.h>

#define NN 100000
#define NE 3200000
#define NB 512
#define BINW 128                  // nodes per bin (bin = node >> 7)
#define NBINS 782                 // ceil(NN / 128); 782*128 = 100096
#define EPB 8192                  // edges per p1/p3 block
#define NBLK 391                  // ceil(NE / EPB)
#define KCHUNK 6400               // r7-proven; 2048 regressed (epilogue+startup not amortized)
#define NKC 16

typedef unsigned short ushort_t;
typedef unsigned int uint_t;

// ---------------- p1: per-block bin-histograms (dst AND src), BOTH graphs ----------------
__global__ __launch_bounds__(256) void k_p1(const int* __restrict__ srcA,
                                            const int* __restrict__ dstA,
                                            const int* __restrict__ srcB,
                                            const int* __restrict__ dstB,
                                            int* __restrict__ cnt4,
                                            int* __restrict__ binTot) {
    __shared__ int hD[NBINS], hS[NBINS];
    int t = threadIdx.x, b = blockIdx.x;
    int g = (b >= NBLK) ? 1 : 0;
    int bb = b - g * NBLK;
    const int* src = g ? srcB : srcA;
    const int* dst = g ? dstB : dstA;
    int* cntD = cnt4 + (size_t)(2 * g)     * NBLK * NBINS;
    int* cntS = cnt4 + (size_t)(2 * g + 1) * NBLK * NBINS;
    int* btD  = binTot + (2 * g) * NBINS;
    int* btS  = binTot + (2 * g + 1) * NBINS;
    for (int i = t; i < NBINS; i += 256) { hD[i] = 0; hS[i] = 0; }
    __syncthreads();
    int base = bb * EPB;
#pragma unroll
    for (int i = 0; i < EPB / 1024; i++) {
        int idx = base + i * 1024 + t * 4;
        if (idx < NE) {  // NE%4==0 -> whole int4 valid
            int4 d4 = *(const int4*)(dst + idx);
            int4 s4 = *(const int4*)(src + idx);
            atomicAdd(&hD[d4.x >> 7], 1); atomicAdd(&hD[d4.y >> 7], 1);
            atomicAdd(&hD[d4.z >> 7], 1); atomicAdd(&hD[d4.w >> 7], 1);
            atomicAdd(&hS[s4.x >> 7], 1); atomicAdd(&hS[s4.y >> 7], 1);
            atomicAdd(&hS[s4.z >> 7], 1); atomicAdd(&hS[s4.w >> 7], 1);
        }
    }
    __syncthreads();
    for (int i = t; i < NBINS; i += 256) {
        int vD = hD[i]; cntD[(size_t)bb * NBINS + i] = vD; if (vD) atomicAdd(btD + i, vD);
        int vS = hS[i]; cntS[(size_t)bb * NBINS + i] = vS; if (vS) atomicAdd(btS + i, vS);
    }
}

// ---------------- scanA: exclusive scan of bin totals, 4 units ----------------
__global__ void k_scanA(const int* __restrict__ binTot, int* __restrict__ binBase,
                        int* __restrict__ off_su, int* __restrict__ off_sv) {
    __shared__ int s[NBINS];
    int u = blockIdx.x;  // 0=D_su 1=S_su 2=D_sv 3=S_sv
    const int* bt = binTot + u * NBINS;
    int* bb = binBase + u * (NBINS + 1);
    int t = threadIdx.x;
    for (int i = t; i < NBINS; i += 256) s[i] = bt[i];
    __syncthreads();
    if (t == 0) {
        int acc = 0;
        for (int i = 0; i < NBINS; i++) { int v = s[i]; s[i] = acc; acc += v; }
    }
    __syncthreads();
    for (int i = t; i < NBINS; i += 256) bb[i] = s[i];
    if (t == 0) bb[NBINS] = NE;
    if (t == 0 && u == 0) { off_su[NN] = NE; off_sv[NN] = NE; }
}

// ---------------- scanB: per-bin prefix over blocks, IN PLACE in cnt ----------------
__global__ void k_scanB(int* __restrict__ cnt4, const int* __restrict__ binBase) {
    __shared__ int s[NBLK];
    int u = blockIdx.x / NBINS, j = blockIdx.x % NBINS;
    int* cnt = cnt4 + (size_t)u * NBLK * NBINS;
    const int* bb = binBase + u * (NBINS + 1);
    int t = threadIdx.x;
    for (int i = t; i < NBLK; i += 256) s[i] = cnt[(size_t)i * NBINS + j];
    __syncthreads();
    if (t == 0) {
        int acc = bb[j];
        for (int i = 0; i < NBLK; i++) { int v = s[i]; s[i] = acc; acc += v; }
    }
    __syncthreads();
    for (int i = t; i < NBLK; i += 256) cnt[(size_t)i * NBINS + j] = s[i];
}

// ---------------- p3: dual scatter into bin order (coalesced cursor loads) ----------------
__global__ __launch_bounds__(256) void k_p3(const int* __restrict__ src,
                                            const int* __restrict__ dst,
                                            const int* __restrict__ cntD,
                                            const int* __restrict__ cntS,
                                            int2* __restrict__ sortedD,
                                            int* __restrict__ sortedS) {
    __shared__ int curD[NBINS], curS[NBINS];
    int t = threadIdx.x, b = blockIdx.x;
    for (int i = t; i < NBINS; i += 256) {
        curD[i] = cntD[(size_t)b * NBINS + i];
        curS[i] = cntS[(size_t)b * NBINS + i];
    }
    __syncthreads();
    int base = b * EPB;
#pragma unroll
    for (int i = 0; i < EPB / 1024; i++) {
        int idx = base + i * 1024 + t * 4;
        if (idx < NE) {
            int4 s4 = *(const int4*)(src + idx);
            int4 d4 = *(const int4*)(dst + idx);
            int p;
            p = atomicAdd(&curD[d4.x >> 7], 1); sortedD[p] = make_int2(s4.x, d4.x);
            p = atomicAdd(&curD[d4.y >> 7], 1); sortedD[p] = make_int2(s4.y, d4.y);
            p = atomicAdd(&curD[d4.z >> 7], 1); sortedD[p] = make_int2(s4.z, d4.z);
            p = atomicAdd(&curD[d4.w >> 7], 1); sortedD[p] = make_int2(s4.w, d4.w);
            p = atomicAdd(&curS[s4.x >> 7], 1); sortedS[p] = s4.x;
            p = atomicAdd(&curS[s4.y >> 7], 1); sortedS[p] = s4.y;
            p = atomicAdd(&curS[s4.z >> 7], 1); sortedS[p] = s4.z;
            p = atomicAdd(&curS[s4.w >> 7], 1); sortedS[p] = s4.w;
        }
    }
}

// ---------------- p4 merged: [0,NBINS) counting-sort -> CSR; [NBINS,2N) src-hist ----------------
__global__ __launch_bounds__(256) void k_p4(const int2* __restrict__ sortedD,
                                            const int* __restrict__ sortedS,
                                            const int* __restrict__ bbD,
                                            const int* __restrict__ bbS,
                                            int* __restrict__ off,
                                            int* __restrict__ edges,
                                            int* __restrict__ cnt_src) {
    __shared__ int hist[BINW], pre[BINW], cur[BINW];
    int t = threadIdx.x;
    if (blockIdx.x < NBINS) {
        int bin = blockIdx.x;
        if (t < BINW) hist[t] = 0;
        __syncthreads();
        int e0 = bbD[bin], e1 = bbD[bin + 1];
        for (int e = e0 + t; e < e1; e += 256)
            atomicAdd(&hist[sortedD[e].y & (BINW - 1)], 1);
        __syncthreads();
        if (t == 0) {
            int a = 0;
            for (int i = 0; i < BINW; i++) { pre[i] = a; a += hist[i]; }
        }
        __syncthreads();
        if (t < BINW) {
            cur[t] = pre[t];
            int node = bin * BINW + t;
            if (node < NN) off[node] = e0 + pre[t];
        }
        __syncthreads();
        for (int e = e0 + t; e < e1; e += 256) {
            int2 ed = sortedD[e];
            int p = atomicAdd(&cur[ed.y & (BINW - 1)], 1);
            edges[e0 + p] = ed.x;
        }
    } else {
        int bin = blockIdx.x - NBINS;
        if (t < BINW) hist[t] = 0;
        __syncthreads();
        int e0 = bbS[bin], e1 = bbS[bin + 1];
        for (int e = e0 + t; e < e1; e += 256)
            atomicAdd(&hist[sortedS[e] & (BINW - 1)], 1);
        __syncthreads();
        if (t < BINW) {
            int node = bin * BINW + t;
            if (node < NN) cnt_src[node] = hist[t];
        }
    }
}

// ---------------- t1: y = (x*sn)@W1 (bf16) ----------------
__global__ __launch_bounds__(256) void k_t1(const float* __restrict__ x,
                                            const float* __restrict__ W1,
                                            const int* __restrict__ cnt_src,
                                            ushort_t* __restrict__ y) {
    __shared__ float sW[2048];
    __shared__ float sx[8 * 65];
    int t = threadIdx.x;
    int node0 = blockIdx.x * 8;
    for (int i = t; i < 2048; i += 256) sW[i] = W1[i];
    for (int i = t; i < 512; i += 256) {
        int r = i >> 6, k = i & 63;
        sx[r * 65 + k] = x[(size_t)(node0 + r) * 64 + k];
    }
    __syncthreads();
    int r = t >> 5, c = t & 31;
    int node = node0 + r;
    float sn = rsqrtf(fmaxf((float)cnt_src[node], 1.0f));
    float acc = 0.0f;
#pragma unroll
    for (int k = 0; k < 64; k++) acc += sx[r * 65 + k] * sW[k * 32 + c];
    acc *= sn;   // row scalar commutes with @W1
    __hip_bfloat16 hb = __float2bfloat16(acc);
    y[(size_t)node * 32 + c] = *reinterpret_cast<ushort_t*>(&hb);
}

// ---------------- t2: y2 = (HT_rows(0..31)*sn)@W2 (bf16) ----------------
__global__ __launch_bounds__(256) void k_t2(const float* __restrict__ HT,
                                            const float* __restrict__ W2,
                                            const int* __restrict__ cnt_src,
                                            ushort_t* __restrict__ y2) {
    __shared__ float sW[512];
    __shared__ float sx[16 * 33];
    int t = threadIdx.x;
    int node0 = blockIdx.x * 16;
    for (int i = t; i < 512; i += 256) sW[i] = W2[i];
    for (int i = t; i < 512; i += 256) {
        int r = i & 15, k = i >> 4;  // r fast -> coalesced over node dim
        sx[r * 33 + k] = HT[(size_t)k * NN + node0 + r];
    }
    __syncthreads();
    int r = t >> 4, c = t & 15;
    int node = node0 + r;
    float sn = rsqrtf(fmaxf((float)cnt_src[node], 1.0f));
    float acc = 0.0f;
#pragma unroll
    for (int k = 0; k < 32; k++) acc += sx[r * 33 + k] * sW[k * 16 + c];
    acc *= sn;
    __hip_bfloat16 hb = __float2bfloat16(acc);
    y2[(size_t)node * 16 + c] = *reinterpret_cast<ushort_t*>(&hb);
}

// ---------------- CSR gather aggregation, packed-uint y ----------------
template <int F, int RELU>
__global__ __launch_bounds__(256) void k_agg(
        const uint_t* __restrict__ y, const int* __restrict__ off,
        const int* __restrict__ edges, const float* __restrict__ bias,
        float* __restrict__ HT, int coloff) {
    constexpr int L = F / 2;
    constexpr int NPB = 256 / L;
    int t = threadIdx.x;
    int g = t / L, c2 = t % L;
    int node = blockIdx.x * NPB + g;
    int e0 = off[node], e1 = off[node + 1];
    int deg = e1 - e0;
    const int* srow = edges + e0;
    float a0 = 0.0f, a1 = 0.0f;
    int e = 0;
    for (; e + 3 < deg; e += 4) {
        int s0 = srow[e], s1 = srow[e + 1], s2 = srow[e + 2], s3 = srow[e + 3];
        uint_t u0 = y[(size_t)s0 * L + c2];
        uint_t u1 = y[(size_t)s1 * L + c2];
        uint_t u2 = y[(size_t)s2 * L + c2];
        uint_t u3 = y[(size_t)s3 * L + c2];
        a0 += __uint_as_float(u0 << 16) + __uint_as_float(u1 << 16)
            + __uint_as_float(u2 << 16) + __uint_as_float(u3 << 16);
        a1 += __uint_as_float(u0 & 0xFFFF0000u) + __uint_as_float(u1 & 0xFFFF0000u)
            + __uint_as_float(u2 & 0xFFFF0000u) + __uint_as_float(u3 & 0xFFFF0000u);
    }
    for (; e < deg; e++) {
        uint_t u = y[(size_t)srow[e] * L + c2];
        a0 += __uint_as_float(u << 16);
        a1 += __uint_as_float(u & 0xFFFF0000u);
    }
    float dn = rsqrtf(fmaxf((float)deg, 1.0f));
    float v0 = a0 * dn + bias[2 * c2];
    float v1 = a1 * dn + bias[2 * c2 + 1];
    if (RELU) { v0 = fmaxf(v0, 0.0f); v1 = fmaxf(v1, 0.0f); }
    HT[(size_t)(coloff + 2 * c2) * NN + node] = v0;
    HT[(size_t)(coloff + 2 * c2 + 1) * NN + node] = v1;
}

// ---------------- pooling v4: 8x8 wave-tile, 4 waves/SIMD for latency hiding ----------------
// grid: (x = 512/32 graph-blocks, y = NKC, z = 12 units); unit u: mat=u/6, j0=(u%6)*8.
// Wave w of a block handles graphs b0 = bx*32 + w*8 (independent; 64 atomics/wave at end).
// VGPR budget: acc 64 + hv 32 + lq 4 + addr ~15 = ~115 <= 128 -> 4 waves/SIMD (r9 fix:
// the old 8x12 tile needed ~190 regs -> 2 waves/SIMD, VALUBusy 32%, 335us).
// KCHUNK stays 6400 (r8: 2048 regressed); min-waves 4 is SAFE here only because the
// live set was sized for it (r3 lesson: cap below demand -> scratch spill disaster).
__global__ __launch_bounds__(256, 4) void k_pool4(
        const float* __restrict__ lenA, const float* __restrict__ lenB,
        const float* __restrict__ HTA, const float* __restrict__ HTB,
        float* __restrict__ pooled) {
    const int u = blockIdx.z;
    const int mat = u / 6;
    const float* __restrict__ len = mat ? lenB : lenA;
    const float* __restrict__ HT  = mat ? HTB : HTA;
    const int colbase = mat ? 48 : 0;
    const int j0 = (u % 6) * 8;
    const int w = threadIdx.x >> 6;
    const int l = threadIdx.x & 63;
    const int b0 = blockIdx.x * 32 + w * 8;

    float acc[8][8];
#pragma unroll
    for (int m = 0; m < 8; m++)
#pragma unroll
        for (int n = 0; n < 8; n++) acc[m][n] = 0.0f;

    const int kc0 = blockIdx.y * KCHUNK;
    const int kc1 = (kc0 + KCHUNK < NN) ? kc0 + KCHUNK : NN;

    for (int ks = kc0; ks < kc1; ks += 256) {
        int k = ks + 4 * l;
        if (k < NN) {  // NN%4==0 -> k..k+3 valid
            float4 hv[8];
#pragma unroll
            for (int n = 0; n < 8; n++)
                hv[n] = *(const float4*)(HT + (size_t)(j0 + n) * NN + k);
            const float* lp = len + (size_t)b0 * NN + k;
#pragma unroll
            for (int m = 0; m < 8; m++) {
                float4 lq = *(const float4*)(lp + (size_t)m * NN);
#pragma unroll
                for (int n = 0; n < 8; n++) {
                    acc[m][n] += lq.x * hv[n].x;
                    acc[m][n] += lq.y * hv[n].y;
                    acc[m][n] += lq.z * hv[n].z;
                    acc[m][n] += lq.w * hv[n].w;
                }
            }
        }
    }

    // butterfly reduce over 64 lanes; lane (m*8+n) owns value (m,n) -> one atomic each
#pragma unroll
    for (int m = 0; m < 8; m++) {
#pragma unroll
        for (int n = 0; n < 8; n++) {
            float v = acc[m][n];
#pragma unroll
            for (int off = 32; off > 0; off >>= 1) v += __shfl_xor(v, off, 64);
            if (l == m * 8 + n)
                atomicAdd(&pooled[(b0 + m) * 96 + colbase + j0 + n], v);
        }
    }
}

// ---------------- MLP head ----------------
__global__ void k_mlp(const float* __restrict__ pooled,
                      const float* __restrict__ fc1w, const float* __restrict__ fc1b,
                      const float* __restrict__ fc2w, const float* __restrict__ fc2b,
                      const float* __restrict__ fc3w, const float* __restrict__ fc3b,
                      float* __restrict__ out) {
    __shared__ float srow[96];
    __shared__ float sh[64];
    __shared__ float sh2[16];
    int b = blockIdx.x, t = threadIdx.x; // 64 threads
    srow[t] = pooled[b * 96 + t];
    if (t < 32) srow[64 + t] = pooled[b * 96 + 64 + t];
    __syncthreads();
    float acc = fc1b[t];
    for (int k = 0; k < 96; k++) acc += srow[k] * fc1w[k * 64 + t];
    sh[t] = fmaxf(acc, 0.0f);
    __syncthreads();
    if (t < 16) {
        float a2 = fc2b[t];
        for (int k = 0; k < 64; k++) a2 += sh[k] * fc2w[k * 16 + t];
        sh2[t] = fmaxf(a2, 0.0f);
    }
    __syncthreads();
    if (t == 0) {
        float a3 = fc3b[0];
        for (int k = 0; k < 16; k++) a3 += sh2[k] * fc3w[k];
        out[b] = a3;
    }
}

extern "C" void kernel_launch(void* const* d_in, const int* in_sizes, int n_in,
                              void* d_out, int out_size, void* d_ws, size_t ws_size,
                              hipStream_t stream) {
    const float* solute_x  = (const float*)d_in[0];
    const float* solvent_x = (const float*)d_in[1];
    const float* su_len    = (const float*)d_in[2];
    const float* sv_len    = (const float*)d_in[3];
    const int*   su_src    = (const int*)d_in[4];
    const int*   su_dst    = (const int*)d_in[5];
    const int*   sv_src    = (const int*)d_in[6];
    const int*   sv_dst    = (const int*)d_in[7];
    const float* W1  = (const float*)d_in[8];
    const float* b1  = (const float*)d_in[9];
    const float* W2  = (const float*)d_in[10];
    const float* b2  = (const float*)d_in[11];
    const float* fc1w = (const float*)d_in[12];
    const float* fc1b = (const float*)d_in[13];
    const float* fc2w = (const float*)d_in[14];
    const float* fc2b = (const float*)d_in[15];
    const float* fc3w = (const float*)d_in[16];
    const float* fc3b = (const float*)d_in[17];
    float* out = (float*)d_out;

    // ---- arena (4B words), total ~77.1 MB ----
    char* ws = (char*)d_ws;
    size_t o = 0;
    auto alloc = [&](size_t elems) { void* p = ws + o * 4; o += elems; return p; };
    int* cnt4     = (int*)alloc((size_t)4 * NBLK * NBINS);  // [D_su][S_su][D_sv][S_sv]
    int* binTot   = (int*)alloc(4 * NBINS);
    int* binBase  = (int*)alloc(4 * (NBINS + 1));
    int* off_su   = (int*)alloc(NN + 1);
    int* off_sv   = (int*)alloc(NN + 1);
    int* csrc_su  = (int*)alloc(NN);
    int* csrc_sv  = (int*)alloc(NN);
    float* pooled = (float*)alloc(NB * 96);
    int* edges_su = (int*)alloc(NE);
    int* edges_sv = (int*)alloc(NE);
    o = (o + 1) & ~(size_t)1;                 // 8B align for int2
    // union region X: build {sortedD int2 NE, sortedS int NE} = 38.4 MB
    //                 compute {ybuf 6.4 + HT_su 19.2 + HT_sv 19.2} = 44.8 MB
    char* X = ws + o * 4;
    int2*   sortedD = (int2*)X;
    int*    sortedS = (int*)(X + (size_t)NE * 8);
    uint_t* ybuf    = (uint_t*)X;
    float*  HT_su   = (float*)(X + (size_t)NN * 64);
    float*  HT_sv   = HT_su + (size_t)NN * 48;

    hipMemsetAsync(binTot, 0, 4 * NBINS * 4, stream);
    hipMemsetAsync(pooled, 0, NB * 96 * 4, stream);

    // ==== phase 1: histograms + scans for BOTH graphs in merged launches ====
    k_p1<<<2 * NBLK, 256, 0, stream>>>(su_src, su_dst, sv_src, sv_dst, cnt4, binTot);
    k_scanA<<<4, 256, 0, stream>>>(binTot, binBase, off_su, off_sv);
    k_scanB<<<4 * NBINS, 256, 0, stream>>>(cnt4, binBase);

    const int* g_src[2]  = {su_src, sv_src};
    const int* g_dst[2]  = {su_dst, sv_dst};
    int* g_off[2]        = {off_su, off_sv};
    int* g_edges[2]      = {edges_su, edges_sv};
    int* g_csrc[2]       = {csrc_su, csrc_sv};

    // per-graph: scatter + counting-sort (sorted buffers reused sequentially)
    for (int g = 0; g < 2; g++) {
        const int* cntD = cnt4 + (size_t)(2 * g) * NBLK * NBINS;
        const int* cntS = cnt4 + (size_t)(2 * g + 1) * NBLK * NBINS;
        const int* bbD  = binBase + (2 * g) * (NBINS + 1);
        const int* bbS  = binBase + (2 * g + 1) * (NBINS + 1);
        k_p3<<<NBLK, 256, 0, stream>>>(g_src[g], g_dst[g], cntD, cntS, sortedD, sortedS);
        k_p4<<<2 * NBINS, 256, 0, stream>>>(sortedD, sortedS, bbD, bbS,
                                            g_off[g], g_edges[g], g_csrc[g]);
    }

    // ==== phase 2: GCN layers (sorted buffers dead; ybuf/HT take over region X) ====
    const float* g_x[2] = {solute_x, solvent_x};
    float* g_HT[2]      = {HT_su, HT_sv};
    for (int g = 0; g < 2; g++) {
        k_t1<<<NN / 8, 256, 0, stream>>>(g_x[g], W1, g_csrc[g], (ushort_t*)ybuf);
        k_agg<32, 1><<<NN / 16, 256, 0, stream>>>(ybuf, g_off[g], g_edges[g], b1, g_HT[g], 0);
        k_t2<<<NN / 16, 256, 0, stream>>>(g_HT[g], W2, g_csrc[g], (ushort_t*)ybuf);
        k_agg<16, 0><<<NN / 32, 256, 0, stream>>>(ybuf, g_off[g], g_edges[g], b2, g_HT[g], 32);
    }

    // ==== pooling + MLP ====
    {
        dim3 gr(NB / 32, NKC, 12);
        k_pool4<<<gr, 256, 0, stream>>>(su_len, sv_len, HT_su, HT_sv, pooled);
    }
    k_mlp<<<NB, 64, 0, stream>>>(pooled, fc1w, fc1b, fc2w, fc2b, fc3w, fc3b, out);
}

// Round 11
// 872.955 us; speedup vs baseline: 1.1015x; 1.1015x over previous
//
#include <hip/hip_runtime.h>
#include <hip/hip_bf16.h>

#define NN 100000
#define NE 3200000
#define NB 512
#define BINW 128                  // nodes per bin (bin = node >> 7)
#define NBINS 782                 // ceil(NN / 128); 782*128 = 100096
#define EPB 8192                  // edges per p1/p3 block
#define NBLK 391                  // ceil(NE / EPB)
#define KCHUNK 6400               // r7-proven; 2048 regressed (epilogue+startup not amortized)
#define NKC 16

typedef unsigned short ushort_t;
typedef unsigned int uint_t;

// ---------------- p1: per-block bin-histograms (dst AND src), BOTH graphs ----------------
__global__ __launch_bounds__(256) void k_p1(const int* __restrict__ srcA,
                                            const int* __restrict__ dstA,
                                            const int* __restrict__ srcB,
                                            const int* __restrict__ dstB,
                                            int* __restrict__ cnt4,
                                            int* __restrict__ binTot) {
    __shared__ int hD[NBINS], hS[NBINS];
    int t = threadIdx.x, b = blockIdx.x;
    int g = (b >= NBLK) ? 1 : 0;
    int bb = b - g * NBLK;
    const int* src = g ? srcB : srcA;
    const int* dst = g ? dstB : dstA;
    int* cntD = cnt4 + (size_t)(2 * g)     * NBLK * NBINS;
    int* cntS = cnt4 + (size_t)(2 * g + 1) * NBLK * NBINS;
    int* btD  = binTot + (2 * g) * NBINS;
    int* btS  = binTot + (2 * g + 1) * NBINS;
    for (int i = t; i < NBINS; i += 256) { hD[i] = 0; hS[i] = 0; }
    __syncthreads();
    int base = bb * EPB;
#pragma unroll
    for (int i = 0; i < EPB / 1024; i++) {
        int idx = base + i * 1024 + t * 4;
        if (idx < NE) {  // NE%4==0 -> whole int4 valid
            int4 d4 = *(const int4*)(dst + idx);
            int4 s4 = *(const int4*)(src + idx);
            atomicAdd(&hD[d4.x >> 7], 1); atomicAdd(&hD[d4.y >> 7], 1);
            atomicAdd(&hD[d4.z >> 7], 1); atomicAdd(&hD[d4.w >> 7], 1);
            atomicAdd(&hS[s4.x >> 7], 1); atomicAdd(&hS[s4.y >> 7], 1);
            atomicAdd(&hS[s4.z >> 7], 1); atomicAdd(&hS[s4.w >> 7], 1);
        }
    }
    __syncthreads();
    for (int i = t; i < NBINS; i += 256) {
        int vD = hD[i]; cntD[(size_t)bb * NBINS + i] = vD; if (vD) atomicAdd(btD + i, vD);
        int vS = hS[i]; cntS[(size_t)bb * NBINS + i] = vS; if (vS) atomicAdd(btS + i, vS);
    }
}

// ---------------- scanA: exclusive scan of bin totals, 4 units ----------------
__global__ void k_scanA(const int* __restrict__ binTot, int* __restrict__ binBase,
                        int* __restrict__ off_su, int* __restrict__ off_sv) {
    __shared__ int s[NBINS];
    int u = blockIdx.x;  // 0=D_su 1=S_su 2=D_sv 3=S_sv
    const int* bt = binTot + u * NBINS;
    int* bb = binBase + u * (NBINS + 1);
    int t = threadIdx.x;
    for (int i = t; i < NBINS; i += 256) s[i] = bt[i];
    __syncthreads();
    if (t == 0) {
        int acc = 0;
        for (int i = 0; i < NBINS; i++) { int v = s[i]; s[i] = acc; acc += v; }
    }
    __syncthreads();
    for (int i = t; i < NBINS; i += 256) bb[i] = s[i];
    if (t == 0) bb[NBINS] = NE;
    if (t == 0 && u == 0) { off_su[NN] = NE; off_sv[NN] = NE; }
}

// ---------------- scanB: per-bin prefix over blocks, IN PLACE in cnt ----------------
__global__ void k_scanB(int* __restrict__ cnt4, const int* __restrict__ binBase) {
    __shared__ int s[NBLK];
    int u = blockIdx.x / NBINS, j = blockIdx.x % NBINS;
    int* cnt = cnt4 + (size_t)u * NBLK * NBINS;
    const int* bb = binBase + u * (NBINS + 1);
    int t = threadIdx.x;
    for (int i = t; i < NBLK; i += 256) s[i] = cnt[(size_t)i * NBINS + j];
    __syncthreads();
    if (t == 0) {
        int acc = bb[j];
        for (int i = 0; i < NBLK; i++) { int v = s[i]; s[i] = acc; acc += v; }
    }
    __syncthreads();
    for (int i = t; i < NBLK; i += 256) cnt[(size_t)i * NBINS + j] = s[i];
}

// ---------------- p3: dual scatter into bin order (coalesced cursor loads) ----------------
__global__ __launch_bounds__(256) void k_p3(const int* __restrict__ src,
                                            const int* __restrict__ dst,
                                            const int* __restrict__ cntD,
                                            const int* __restrict__ cntS,
                                            int2* __restrict__ sortedD,
                                            int* __restrict__ sortedS) {
    __shared__ int curD[NBINS], curS[NBINS];
    int t = threadIdx.x, b = blockIdx.x;
    for (int i = t; i < NBINS; i += 256) {
        curD[i] = cntD[(size_t)b * NBINS + i];
        curS[i] = cntS[(size_t)b * NBINS + i];
    }
    __syncthreads();
    int base = b * EPB;
#pragma unroll
    for (int i = 0; i < EPB / 1024; i++) {
        int idx = base + i * 1024 + t * 4;
        if (idx < NE) {
            int4 s4 = *(const int4*)(src + idx);
            int4 d4 = *(const int4*)(dst + idx);
            int p;
            p = atomicAdd(&curD[d4.x >> 7], 1); sortedD[p] = make_int2(s4.x, d4.x);
            p = atomicAdd(&curD[d4.y >> 7], 1); sortedD[p] = make_int2(s4.y, d4.y);
            p = atomicAdd(&curD[d4.z >> 7], 1); sortedD[p] = make_int2(s4.z, d4.z);
            p = atomicAdd(&curD[d4.w >> 7], 1); sortedD[p] = make_int2(s4.w, d4.w);
            p = atomicAdd(&curS[s4.x >> 7], 1); sortedS[p] = s4.x;
            p = atomicAdd(&curS[s4.y >> 7], 1); sortedS[p] = s4.y;
            p = atomicAdd(&curS[s4.z >> 7], 1); sortedS[p] = s4.z;
            p = atomicAdd(&curS[s4.w >> 7], 1); sortedS[p] = s4.w;
        }
    }
}

// ---------------- p4 merged: [0,NBINS) counting-sort -> CSR; [NBINS,2N) src-hist ----------------
__global__ __launch_bounds__(256) void k_p4(const int2* __restrict__ sortedD,
                                            const int* __restrict__ sortedS,
                                            const int* __restrict__ bbD,
                                            const int* __restrict__ bbS,
                                            int* __restrict__ off,
                                            int* __restrict__ edges,
                                            int* __restrict__ cnt_src) {
    __shared__ int hist[BINW], pre[BINW], cur[BINW];
    int t = threadIdx.x;
    if (blockIdx.x < NBINS) {
        int bin = blockIdx.x;
        if (t < BINW) hist[t] = 0;
        __syncthreads();
        int e0 = bbD[bin], e1 = bbD[bin + 1];
        for (int e = e0 + t; e < e1; e += 256)
            atomicAdd(&hist[sortedD[e].y & (BINW - 1)], 1);
        __syncthreads();
        if (t == 0) {
            int a = 0;
            for (int i = 0; i < BINW; i++) { pre[i] = a; a += hist[i]; }
        }
        __syncthreads();
        if (t < BINW) {
            cur[t] = pre[t];
            int node = bin * BINW + t;
            if (node < NN) off[node] = e0 + pre[t];
        }
        __syncthreads();
        for (int e = e0 + t; e < e1; e += 256) {
            int2 ed = sortedD[e];
            int p = atomicAdd(&cur[ed.y & (BINW - 1)], 1);
            edges[e0 + p] = ed.x;
        }
    } else {
        int bin = blockIdx.x - NBINS;
        if (t < BINW) hist[t] = 0;
        __syncthreads();
        int e0 = bbS[bin], e1 = bbS[bin + 1];
        for (int e = e0 + t; e < e1; e += 256)
            atomicAdd(&hist[sortedS[e] & (BINW - 1)], 1);
        __syncthreads();
        if (t < BINW) {
            int node = bin * BINW + t;
            if (node < NN) cnt_src[node] = hist[t];
        }
    }
}

// ---------------- t1: y = (x*sn)@W1 (bf16) ----------------
__global__ __launch_bounds__(256) void k_t1(const float* __restrict__ x,
                                            const float* __restrict__ W1,
                                            const int* __restrict__ cnt_src,
                                            ushort_t* __restrict__ y) {
    __shared__ float sW[2048];
    __shared__ float sx[8 * 65];
    int t = threadIdx.x;
    int node0 = blockIdx.x * 8;
    for (int i = t; i < 2048; i += 256) sW[i] = W1[i];
    for (int i = t; i < 512; i += 256) {
        int r = i >> 6, k = i & 63;
        sx[r * 65 + k] = x[(size_t)(node0 + r) * 64 + k];
    }
    __syncthreads();
    int r = t >> 5, c = t & 31;
    int node = node0 + r;
    float sn = rsqrtf(fmaxf((float)cnt_src[node], 1.0f));
    float acc = 0.0f;
#pragma unroll
    for (int k = 0; k < 64; k++) acc += sx[r * 65 + k] * sW[k * 32 + c];
    acc *= sn;   // row scalar commutes with @W1
    __hip_bfloat16 hb = __float2bfloat16(acc);
    y[(size_t)node * 32 + c] = *reinterpret_cast<ushort_t*>(&hb);
}

// ---------------- t2: y2 = (HT_rows(0..31)*sn)@W2 (bf16) ----------------
__global__ __launch_bounds__(256) void k_t2(const float* __restrict__ HT,
                                            const float* __restrict__ W2,
                                            const int* __restrict__ cnt_src,
                                            ushort_t* __restrict__ y2) {
    __shared__ float sW[512];
    __shared__ float sx[16 * 33];
    int t = threadIdx.x;
    int node0 = blockIdx.x * 16;
    for (int i = t; i < 512; i += 256) sW[i] = W2[i];
    for (int i = t; i < 512; i += 256) {
        int r = i & 15, k = i >> 4;  // r fast -> coalesced over node dim
        sx[r * 33 + k] = HT[(size_t)k * NN + node0 + r];
    }
    __syncthreads();
    int r = t >> 4, c = t & 15;
    int node = node0 + r;
    float sn = rsqrtf(fmaxf((float)cnt_src[node], 1.0f));
    float acc = 0.0f;
#pragma unroll
    for (int k = 0; k < 32; k++) acc += sx[r * 33 + k] * sW[k * 16 + c];
    acc *= sn;
    __hip_bfloat16 hb = __float2bfloat16(acc);
    y2[(size_t)node * 16 + c] = *reinterpret_cast<ushort_t*>(&hb);
}

// ---------------- CSR gather aggregation, packed-uint y ----------------
template <int F, int RELU>
__global__ __launch_bounds__(256) void k_agg(
        const uint_t* __restrict__ y, const int* __restrict__ off,
        const int* __restrict__ edges, const float* __restrict__ bias,
        float* __restrict__ HT, int coloff) {
    constexpr int L = F / 2;
    constexpr int NPB = 256 / L;
    int t = threadIdx.x;
    int g = t / L, c2 = t % L;
    int node = blockIdx.x * NPB + g;
    int e0 = off[node], e1 = off[node + 1];
    int deg = e1 - e0;
    const int* srow = edges + e0;
    float a0 = 0.0f, a1 = 0.0f;
    int e = 0;
    for (; e + 3 < deg; e += 4) {
        int s0 = srow[e], s1 = srow[e + 1], s2 = srow[e + 2], s3 = srow[e + 3];
        uint_t u0 = y[(size_t)s0 * L + c2];
        uint_t u1 = y[(size_t)s1 * L + c2];
        uint_t u2 = y[(size_t)s2 * L + c2];
        uint_t u3 = y[(size_t)s3 * L + c2];
        a0 += __uint_as_float(u0 << 16) + __uint_as_float(u1 << 16)
            + __uint_as_float(u2 << 16) + __uint_as_float(u3 << 16);
        a1 += __uint_as_float(u0 & 0xFFFF0000u) + __uint_as_float(u1 & 0xFFFF0000u)
            + __uint_as_float(u2 & 0xFFFF0000u) + __uint_as_float(u3 & 0xFFFF0000u);
    }
    for (; e < deg; e++) {
        uint_t u = y[(size_t)srow[e] * L + c2];
        a0 += __uint_as_float(u << 16);
        a1 += __uint_as_float(u & 0xFFFF0000u);
    }
    float dn = rsqrtf(fmaxf((float)deg, 1.0f));
    float v0 = a0 * dn + bias[2 * c2];
    float v1 = a1 * dn + bias[2 * c2 + 1];
    if (RELU) { v0 = fmaxf(v0, 0.0f); v1 = fmaxf(v1, 0.0f); }
    HT[(size_t)(coloff + 2 * c2) * NN + node] = v0;
    HT[(size_t)(coloff + 2 * c2 + 1) * NN + node] = v1;
}

// ---------------- pooling v5: 8x8 wave-tile, 6 waves/block covering all 48 cols ----------------
// Lessons combined: pool3 (all cols of a mat in ONE block -> len L1-reuse, FETCH 351MB) +
// pool4 (8x8 tile -> low VGPR, more waves/SIMD, 2.7TB/s streaming). pool4's z-split of
// column groups across blocks tripled FETCH to 985MB -> never split cols across blocks.
// Block: 384 threads = 6 waves; wave w covers cols j0=w*8 of one mat for 8 graphs.
// VGPR demand ~110 (acc 64 + hv 32 + addr) <= cap 128 from launch_bounds(384,4) (r3 margin ok).
// KCHUNK stays 6400 (r8: 2048 regressed).
__global__ __launch_bounds__(384, 4) void k_pool5(
        const float* __restrict__ lenA, const float* __restrict__ lenB,
        const float* __restrict__ HTA, const float* __restrict__ HTB,
        float* __restrict__ pooled) {
    const int mat = blockIdx.z;
    const float* __restrict__ len = mat ? lenB : lenA;
    const float* __restrict__ HT  = mat ? HTB : HTA;
    const int colbase = mat ? 48 : 0;
    const int b0 = blockIdx.x * 8;
    const int w = threadIdx.x / 64;      // 0..5 -> col group
    const int l = threadIdx.x & 63;
    const int j0 = w * 8;

    float acc[8][8];
#pragma unroll
    for (int m = 0; m < 8; m++)
#pragma unroll
        for (int n = 0; n < 8; n++) acc[m][n] = 0.0f;

    const int kc0 = blockIdx.y * KCHUNK;
    const int kc1 = (kc0 + KCHUNK < NN) ? kc0 + KCHUNK : NN;

    for (int ks = kc0; ks < kc1; ks += 256) {
        int k = ks + 4 * l;
        if (k < NN) {  // NN%4==0 -> k..k+3 valid
            float4 hv[8];
#pragma unroll
            for (int n = 0; n < 8; n++)
                hv[n] = *(const float4*)(HT + (size_t)(j0 + n) * NN + k);
            const float* lp = len + (size_t)b0 * NN + k;
#pragma unroll
            for (int m = 0; m < 8; m++) {
                float4 lq = *(const float4*)(lp + (size_t)m * NN);
#pragma unroll
                for (int n = 0; n < 8; n++) {
                    acc[m][n] += lq.x * hv[n].x;
                    acc[m][n] += lq.y * hv[n].y;
                    acc[m][n] += lq.z * hv[n].z;
                    acc[m][n] += lq.w * hv[n].w;
                }
            }
        }
    }

    // butterfly reduce over 64 lanes; lane (m*8+n) owns value (m,n) -> one atomic each
#pragma unroll
    for (int m = 0; m < 8; m++) {
#pragma unroll
        for (int n = 0; n < 8; n++) {
            float v = acc[m][n];
#pragma unroll
            for (int off = 32; off > 0; off >>= 1) v += __shfl_xor(v, off, 64);
            if (l == m * 8 + n)
                atomicAdd(&pooled[(b0 + m) * 96 + colbase + j0 + n], v);
        }
    }
}

// ---------------- MLP head ----------------
__global__ void k_mlp(const float* __restrict__ pooled,
                      const float* __restrict__ fc1w, const float* __restrict__ fc1b,
                      const float* __restrict__ fc2w, const float* __restrict__ fc2b,
                      const float* __restrict__ fc3w, const float* __restrict__ fc3b,
                      float* __restrict__ out) {
    __shared__ float srow[96];
    __shared__ float sh[64];
    __shared__ float sh2[16];
    int b = blockIdx.x, t = threadIdx.x; // 64 threads
    srow[t] = pooled[b * 96 + t];
    if (t < 32) srow[64 + t] = pooled[b * 96 + 64 + t];
    __syncthreads();
    float acc = fc1b[t];
    for (int k = 0; k < 96; k++) acc += srow[k] * fc1w[k * 64 + t];
    sh[t] = fmaxf(acc, 0.0f);
    __syncthreads();
    if (t < 16) {
        float a2 = fc2b[t];
        for (int k = 0; k < 64; k++) a2 += sh[k] * fc2w[k * 16 + t];
        sh2[t] = fmaxf(a2, 0.0f);
    }
    __syncthreads();
    if (t == 0) {
        float a3 = fc3b[0];
        for (int k = 0; k < 16; k++) a3 += sh2[k] * fc3w[k];
        out[b] = a3;
    }
}

extern "C" void kernel_launch(void* const* d_in, const int* in_sizes, int n_in,
                              void* d_out, int out_size, void* d_ws, size_t ws_size,
                              hipStream_t stream) {
    const float* solute_x  = (const float*)d_in[0];
    const float* solvent_x = (const float*)d_in[1];
    const float* su_len    = (const float*)d_in[2];
    const float* sv_len    = (const float*)d_in[3];
    const int*   su_src    = (const int*)d_in[4];
    const int*   su_dst    = (const int*)d_in[5];
    const int*   sv_src    = (const int*)d_in[6];
    const int*   sv_dst    = (const int*)d_in[7];
    const float* W1  = (const float*)d_in[8];
    const float* b1  = (const float*)d_in[9];
    const float* W2  = (const float*)d_in[10];
    const float* b2  = (const float*)d_in[11];
    const float* fc1w = (const float*)d_in[12];
    const float* fc1b = (const float*)d_in[13];
    const float* fc2w = (const float*)d_in[14];
    const float* fc2b = (const float*)d_in[15];
    const float* fc3w = (const float*)d_in[16];
    const float* fc3b = (const float*)d_in[17];
    float* out = (float*)d_out;

    // ---- arena (4B words), total ~77.1 MB ----
    char* ws = (char*)d_ws;
    size_t o = 0;
    auto alloc = [&](size_t elems) { void* p = ws + o * 4; o += elems; return p; };
    int* cnt4     = (int*)alloc((size_t)4 * NBLK * NBINS);  // [D_su][S_su][D_sv][S_sv]
    int* binTot   = (int*)alloc(4 * NBINS);
    int* binBase  = (int*)alloc(4 * (NBINS + 1));
    int* off_su   = (int*)alloc(NN + 1);
    int* off_sv   = (int*)alloc(NN + 1);
    int* csrc_su  = (int*)alloc(NN);
    int* csrc_sv  = (int*)alloc(NN);
    float* pooled = (float*)alloc(NB * 96);
    int* edges_su = (int*)alloc(NE);
    int* edges_sv = (int*)alloc(NE);
    o = (o + 1) & ~(size_t)1;                 // 8B align for int2
    // union region X: build {sortedD int2 NE, sortedS int NE} = 38.4 MB
    //                 compute {ybuf 6.4 + HT_su 19.2 + HT_sv 19.2} = 44.8 MB
    char* X = ws + o * 4;
    int2*   sortedD = (int2*)X;
    int*    sortedS = (int*)(X + (size_t)NE * 8);
    uint_t* ybuf    = (uint_t*)X;
    float*  HT_su   = (float*)(X + (size_t)NN * 64);
    float*  HT_sv   = HT_su + (size_t)NN * 48;

    hipMemsetAsync(binTot, 0, 4 * NBINS * 4, stream);
    hipMemsetAsync(pooled, 0, NB * 96 * 4, stream);

    // ==== phase 1: histograms + scans for BOTH graphs in merged launches ====
    k_p1<<<2 * NBLK, 256, 0, stream>>>(su_src, su_dst, sv_src, sv_dst, cnt4, binTot);
    k_scanA<<<4, 256, 0, stream>>>(binTot, binBase, off_su, off_sv);
    k_scanB<<<4 * NBINS, 256, 0, stream>>>(cnt4, binBase);

    const int* g_src[2]  = {su_src, sv_src};
    const int* g_dst[2]  = {su_dst, sv_dst};
    int* g_off[2]        = {off_su, off_sv};
    int* g_edges[2]      = {edges_su, edges_sv};
    int* g_csrc[2]       = {csrc_su, csrc_sv};

    // per-graph: scatter + counting-sort (sorted buffers reused sequentially)
    for (int g = 0; g < 2; g++) {
        const int* cntD = cnt4 + (size_t)(2 * g) * NBLK * NBINS;
        const int* cntS = cnt4 + (size_t)(2 * g + 1) * NBLK * NBINS;
        const int* bbD  = binBase + (2 * g) * (NBINS + 1);
        const int* bbS  = binBase + (2 * g + 1) * (NBINS + 1);
        k_p3<<<NBLK, 256, 0, stream>>>(g_src[g], g_dst[g], cntD, cntS, sortedD, sortedS);
        k_p4<<<2 * NBINS, 256, 0, stream>>>(sortedD, sortedS, bbD, bbS,
                                            g_off[g], g_edges[g], g_csrc[g]);
    }

    // ==== phase 2: GCN layers (sorted buffers dead; ybuf/HT take over region X) ====
    const float* g_x[2] = {solute_x, solvent_x};
    float* g_HT[2]      = {HT_su, HT_sv};
    for (int g = 0; g < 2; g++) {
        k_t1<<<NN / 8, 256, 0, stream>>>(g_x[g], W1, g_csrc[g], (ushort_t*)ybuf);
        k_agg<32, 1><<<NN / 16, 256, 0, stream>>>(ybuf, g_off[g], g_edges[g], b1, g_HT[g], 0);
        k_t2<<<NN / 16, 256, 0, stream>>>(g_HT[g], W2, g_csrc[g], (ushort_t*)ybuf);
        k_agg<16, 0><<<NN / 32, 256, 0, stream>>>(ybuf, g_off[g], g_edges[g], b2, g_HT[g], 32);
    }

    // ==== pooling + MLP ====
    {
        dim3 gr(NB / 8, NKC, 2);
        k_pool5<<<gr, 384, 0, stream>>>(su_len, sv_len, HT_su, HT_sv, pooled);
    }
    k_mlp<<<NB, 64, 0, stream>>>(pooled, fc1w, fc1b, fc2w, fc2b, fc3w, fc3b, out);
}

// Round 12
// 845.995 us; speedup vs baseline: 1.1366x; 1.0319x over previous
//
#include <hip/hip_runtime.h>
#include <hip/hip_bf16.h>

#define NN 100000
#define NE 3200000
#define NB 512
#define BINW 128                  // nodes per bin (bin = node >> 7)
#define NBINS 782                 // ceil(NN / 128); 782*128 = 100096
#define EPB 8192                  // edges per p1/p3 block
#define NBLK 391                  // ceil(NE / EPB)
#define KCHUNK 6400               // r7-proven; 2048 regressed (epilogue+startup not amortized)
#define NKC 16

typedef unsigned short ushort_t;
typedef unsigned int uint_t;

// ---------------- p1: per-block bin-histograms (dst AND src), BOTH graphs ----------------
__global__ __launch_bounds__(256) void k_p1(const int* __restrict__ srcA,
                                            const int* __restrict__ dstA,
                                            const int* __restrict__ srcB,
                                            const int* __restrict__ dstB,
                                            int* __restrict__ cnt4,
                                            int* __restrict__ binTot) {
    __shared__ int hD[NBINS], hS[NBINS];
    int t = threadIdx.x, b = blockIdx.x;
    int g = (b >= NBLK) ? 1 : 0;
    int bb = b - g * NBLK;
    const int* src = g ? srcB : srcA;
    const int* dst = g ? dstB : dstA;
    int* cntD = cnt4 + (size_t)(2 * g)     * NBLK * NBINS;
    int* cntS = cnt4 + (size_t)(2 * g + 1) * NBLK * NBINS;
    int* btD  = binTot + (2 * g) * NBINS;
    int* btS  = binTot + (2 * g + 1) * NBINS;
    for (int i = t; i < NBINS; i += 256) { hD[i] = 0; hS[i] = 0; }
    __syncthreads();
    int base = bb * EPB;
#pragma unroll
    for (int i = 0; i < EPB / 1024; i++) {
        int idx = base + i * 1024 + t * 4;
        if (idx < NE) {  // NE%4==0 -> whole int4 valid
            int4 d4 = *(const int4*)(dst + idx);
            int4 s4 = *(const int4*)(src + idx);
            atomicAdd(&hD[d4.x >> 7], 1); atomicAdd(&hD[d4.y >> 7], 1);
            atomicAdd(&hD[d4.z >> 7], 1); atomicAdd(&hD[d4.w >> 7], 1);
            atomicAdd(&hS[s4.x >> 7], 1); atomicAdd(&hS[s4.y >> 7], 1);
            atomicAdd(&hS[s4.z >> 7], 1); atomicAdd(&hS[s4.w >> 7], 1);
        }
    }
    __syncthreads();
    for (int i = t; i < NBINS; i += 256) {
        int vD = hD[i]; cntD[(size_t)bb * NBINS + i] = vD; if (vD) atomicAdd(btD + i, vD);
        int vS = hS[i]; cntS[(size_t)bb * NBINS + i] = vS; if (vS) atomicAdd(btS + i, vS);
    }
}

// ---------------- scanA: exclusive scan of bin totals, 4 units ----------------
__global__ void k_scanA(const int* __restrict__ binTot, int* __restrict__ binBase,
                        int* __restrict__ off_su, int* __restrict__ off_sv) {
    __shared__ int s[NBINS];
    int u = blockIdx.x;  // 0=D_su 1=S_su 2=D_sv 3=S_sv
    const int* bt = binTot + u * NBINS;
    int* bb = binBase + u * (NBINS + 1);
    int t = threadIdx.x;
    for (int i = t; i < NBINS; i += 256) s[i] = bt[i];
    __syncthreads();
    if (t == 0) {
        int acc = 0;
        for (int i = 0; i < NBINS; i++) { int v = s[i]; s[i] = acc; acc += v; }
    }
    __syncthreads();
    for (int i = t; i < NBINS; i += 256) bb[i] = s[i];
    if (t == 0) bb[NBINS] = NE;
    if (t == 0 && u == 0) { off_su[NN] = NE; off_sv[NN] = NE; }
}

// ---------------- scanB: per-bin prefix over blocks, IN PLACE in cnt ----------------
__global__ void k_scanB(int* __restrict__ cnt4, const int* __restrict__ binBase) {
    __shared__ int s[NBLK];
    int u = blockIdx.x / NBINS, j = blockIdx.x % NBINS;
    int* cnt = cnt4 + (size_t)u * NBLK * NBINS;
    const int* bb = binBase + u * (NBINS + 1);
    int t = threadIdx.x;
    for (int i = t; i < NBLK; i += 256) s[i] = cnt[(size_t)i * NBINS + j];
    __syncthreads();
    if (t == 0) {
        int acc = bb[j];
        for (int i = 0; i < NBLK; i++) { int v = s[i]; s[i] = acc; acc += v; }
    }
    __syncthreads();
    for (int i = t; i < NBLK; i += 256) cnt[(size_t)i * NBINS + j] = s[i];
}

// ---------------- p3: dual scatter into bin order (coalesced cursor loads) ----------------
__global__ __launch_bounds__(256) void k_p3(const int* __restrict__ src,
                                            const int* __restrict__ dst,
                                            const int* __restrict__ cntD,
                                            const int* __restrict__ cntS,
                                            int2* __restrict__ sortedD,
                                            int* __restrict__ sortedS) {
    __shared__ int curD[NBINS], curS[NBINS];
    int t = threadIdx.x, b = blockIdx.x;
    for (int i = t; i < NBINS; i += 256) {
        curD[i] = cntD[(size_t)b * NBINS + i];
        curS[i] = cntS[(size_t)b * NBINS + i];
    }
    __syncthreads();
    int base = b * EPB;
#pragma unroll
    for (int i = 0; i < EPB / 1024; i++) {
        int idx = base + i * 1024 + t * 4;
        if (idx < NE) {
            int4 s4 = *(const int4*)(src + idx);
            int4 d4 = *(const int4*)(dst + idx);
            int p;
            p = atomicAdd(&curD[d4.x >> 7], 1); sortedD[p] = make_int2(s4.x, d4.x);
            p = atomicAdd(&curD[d4.y >> 7], 1); sortedD[p] = make_int2(s4.y, d4.y);
            p = atomicAdd(&curD[d4.z >> 7], 1); sortedD[p] = make_int2(s4.z, d4.z);
            p = atomicAdd(&curD[d4.w >> 7], 1); sortedD[p] = make_int2(s4.w, d4.w);
            p = atomicAdd(&curS[s4.x >> 7], 1); sortedS[p] = s4.x;
            p = atomicAdd(&curS[s4.y >> 7], 1); sortedS[p] = s4.y;
            p = atomicAdd(&curS[s4.z >> 7], 1); sortedS[p] = s4.z;
            p = atomicAdd(&curS[s4.w >> 7], 1); sortedS[p] = s4.w;
        }
    }
}

// ---------------- p4 merged: [0,NBINS) counting-sort -> CSR; [NBINS,2N) src-hist ----------------
__global__ __launch_bounds__(256) void k_p4(const int2* __restrict__ sortedD,
                                            const int* __restrict__ sortedS,
                                            const int* __restrict__ bbD,
                                            const int* __restrict__ bbS,
                                            int* __restrict__ off,
                                            int* __restrict__ edges,
                                            int* __restrict__ cnt_src) {
    __shared__ int hist[BINW], pre[BINW], cur[BINW];
    int t = threadIdx.x;
    if (blockIdx.x < NBINS) {
        int bin = blockIdx.x;
        if (t < BINW) hist[t] = 0;
        __syncthreads();
        int e0 = bbD[bin], e1 = bbD[bin + 1];
        for (int e = e0 + t; e < e1; e += 256)
            atomicAdd(&hist[sortedD[e].y & (BINW - 1)], 1);
        __syncthreads();
        if (t == 0) {
            int a = 0;
            for (int i = 0; i < BINW; i++) { pre[i] = a; a += hist[i]; }
        }
        __syncthreads();
        if (t < BINW) {
            cur[t] = pre[t];
            int node = bin * BINW + t;
            if (node < NN) off[node] = e0 + pre[t];
        }
        __syncthreads();
        for (int e = e0 + t; e < e1; e += 256) {
            int2 ed = sortedD[e];
            int p = atomicAdd(&cur[ed.y & (BINW - 1)], 1);
            edges[e0 + p] = ed.x;
        }
    } else {
        int bin = blockIdx.x - NBINS;
        if (t < BINW) hist[t] = 0;
        __syncthreads();
        int e0 = bbS[bin], e1 = bbS[bin + 1];
        for (int e = e0 + t; e < e1; e += 256)
            atomicAdd(&hist[sortedS[e] & (BINW - 1)], 1);
        __syncthreads();
        if (t < BINW) {
            int node = bin * BINW + t;
            if (node < NN) cnt_src[node] = hist[t];
        }
    }
}

// ---------------- t1: y = (x*sn)@W1 (bf16) ----------------
__global__ __launch_bounds__(256) void k_t1(const float* __restrict__ x,
                                            const float* __restrict__ W1,
                                            const int* __restrict__ cnt_src,
                                            ushort_t* __restrict__ y) {
    __shared__ float sW[2048];
    __shared__ float sx[8 * 65];
    int t = threadIdx.x;
    int node0 = blockIdx.x * 8;
    for (int i = t; i < 2048; i += 256) sW[i] = W1[i];
    for (int i = t; i < 512; i += 256) {
        int r = i >> 6, k = i & 63;
        sx[r * 65 + k] = x[(size_t)(node0 + r) * 64 + k];
    }
    __syncthreads();
    int r = t >> 5, c = t & 31;
    int node = node0 + r;
    float sn = rsqrtf(fmaxf((float)cnt_src[node], 1.0f));
    float acc = 0.0f;
#pragma unroll
    for (int k = 0; k < 64; k++) acc += sx[r * 65 + k] * sW[k * 32 + c];
    acc *= sn;   // row scalar commutes with @W1
    __hip_bfloat16 hb = __float2bfloat16(acc);
    y[(size_t)node * 32 + c] = *reinterpret_cast<ushort_t*>(&hb);
}

// ---------------- t2: y2 = (HT_rows(0..31)*sn)@W2 (bf16) ----------------
__global__ __launch_bounds__(256) void k_t2(const float* __restrict__ HT,
                                            const float* __restrict__ W2,
                                            const int* __restrict__ cnt_src,
                                            ushort_t* __restrict__ y2) {
    __shared__ float sW[512];
    __shared__ float sx[16 * 33];
    int t = threadIdx.x;
    int node0 = blockIdx.x * 16;
    for (int i = t; i < 512; i += 256) sW[i] = W2[i];
    for (int i = t; i < 512; i += 256) {
        int r = i & 15, k = i >> 4;  // r fast -> coalesced over node dim
        sx[r * 33 + k] = HT[(size_t)k * NN + node0 + r];
    }
    __syncthreads();
    int r = t >> 4, c = t & 15;
    int node = node0 + r;
    float sn = rsqrtf(fmaxf((float)cnt_src[node], 1.0f));
    float acc = 0.0f;
#pragma unroll
    for (int k = 0; k < 32; k++) acc += sx[r * 33 + k] * sW[k * 16 + c];
    acc *= sn;
    __hip_bfloat16 hb = __float2bfloat16(acc);
    y2[(size_t)node * 16 + c] = *reinterpret_cast<ushort_t*>(&hb);
}

// ---------------- CSR gather aggregation, packed-uint y ----------------
template <int F, int RELU>
__global__ __launch_bounds__(256) void k_agg(
        const uint_t* __restrict__ y, const int* __restrict__ off,
        const int* __restrict__ edges, const float* __restrict__ bias,
        float* __restrict__ HT, int coloff) {
    constexpr int L = F / 2;
    constexpr int NPB = 256 / L;
    int t = threadIdx.x;
    int g = t / L, c2 = t % L;
    int node = blockIdx.x * NPB + g;
    int e0 = off[node], e1 = off[node + 1];
    int deg = e1 - e0;
    const int* srow = edges + e0;
    float a0 = 0.0f, a1 = 0.0f;
    int e = 0;
    for (; e + 3 < deg; e += 4) {
        int s0 = srow[e], s1 = srow[e + 1], s2 = srow[e + 2], s3 = srow[e + 3];
        uint_t u0 = y[(size_t)s0 * L + c2];
        uint_t u1 = y[(size_t)s1 * L + c2];
        uint_t u2 = y[(size_t)s2 * L + c2];
        uint_t u3 = y[(size_t)s3 * L + c2];
        a0 += __uint_as_float(u0 << 16) + __uint_as_float(u1 << 16)
            + __uint_as_float(u2 << 16) + __uint_as_float(u3 << 16);
        a1 += __uint_as_float(u0 & 0xFFFF0000u) + __uint_as_float(u1 & 0xFFFF0000u)
            + __uint_as_float(u2 & 0xFFFF0000u) + __uint_as_float(u3 & 0xFFFF0000u);
    }
    for (; e < deg; e++) {
        uint_t u = y[(size_t)srow[e] * L + c2];
        a0 += __uint_as_float(u << 16);
        a1 += __uint_as_float(u & 0xFFFF0000u);
    }
    float dn = rsqrtf(fmaxf((float)deg, 1.0f));
    float v0 = a0 * dn + bias[2 * c2];
    float v1 = a1 * dn + bias[2 * c2 + 1];
    if (RELU) { v0 = fmaxf(v0, 0.0f); v1 = fmaxf(v1, 0.0f); }
    HT[(size_t)(coloff + 2 * c2) * NN + node] = v0;
    HT[(size_t)(coloff + 2 * c2 + 1) * NN + node] = v1;
}

// ---------------- pooling v6: 8 waves x (8 graphs x 6 cols), guard-free main loop ----------
// Traffic lesson (pool4->5): all 48 cols of a mat in ONE block -> len L1-reuse (FETCH ~410MB).
// Occupancy lesson (pool4): 4 waves/SIMD needs small tile. 8x6 tile: acc 48 + hv 24 + lq 4
// + addr ~16 = ~92 VGPR <= 128 cap from launch_bounds(512,4) (r3 margin check ok).
// Latency lesson (new): the old `if (k<NN)` inside the k-loop made every load control-
// dependent -> no software pipelining. Main loop is now guard-free (KCHUNK%256==0), the
// 160-elem tail of the last chunk is a separate masked step.
// KCHUNK stays 6400 (r8: 2048 regressed).
__global__ __launch_bounds__(512, 4) void k_pool6(
        const float* __restrict__ lenA, const float* __restrict__ lenB,
        const float* __restrict__ HTA, const float* __restrict__ HTB,
        float* __restrict__ pooled) {
    const int mat = blockIdx.z;
    const float* __restrict__ len = mat ? lenB : lenA;
    const float* __restrict__ HT  = mat ? HTB : HTA;
    const int colbase = mat ? 48 : 0;
    const int b0 = blockIdx.x * 8;
    const int w = threadIdx.x >> 6;      // 0..7 -> col group
    const int l = threadIdx.x & 63;
    const int j0 = w * 6;

    float acc[8][6];
#pragma unroll
    for (int m = 0; m < 8; m++)
#pragma unroll
        for (int n = 0; n < 6; n++) acc[m][n] = 0.0f;

    const int kc0 = blockIdx.y * KCHUNK;
    const int kc1 = (kc0 + KCHUNK < NN) ? kc0 + KCHUNK : NN;
    const int nfull = (kc1 - kc0) >> 8;        // full 256-wide steps (guard-free)
    const int rem   = (kc1 - kc0) & 255;       // tail elements (only last chunk: 160)

    const float* lp0 = len + (size_t)b0 * NN + kc0 + 4 * l;
    const float* hp0 = HT + (size_t)j0 * NN + kc0 + 4 * l;

    for (int s = 0; s < nfull; s++) {
        int koff = s * 256;
        float4 hv[6];
#pragma unroll
        for (int n = 0; n < 6; n++)
            hv[n] = *(const float4*)(hp0 + (size_t)n * NN + koff);
#pragma unroll
        for (int m = 0; m < 8; m++) {
            float4 lq = *(const float4*)(lp0 + (size_t)m * NN + koff);
#pragma unroll
            for (int n = 0; n < 6; n++) {
                acc[m][n] += lq.x * hv[n].x;
                acc[m][n] += lq.y * hv[n].y;
                acc[m][n] += lq.z * hv[n].z;
                acc[m][n] += lq.w * hv[n].w;
            }
        }
    }
    if (rem && 4 * l < rem) {  // rem%4==0 -> whole float4 valid for active lanes
        int koff = nfull * 256;
        float4 hv[6];
#pragma unroll
        for (int n = 0; n < 6; n++)
            hv[n] = *(const float4*)(hp0 + (size_t)n * NN + koff);
#pragma unroll
        for (int m = 0; m < 8; m++) {
            float4 lq = *(const float4*)(lp0 + (size_t)m * NN + koff);
#pragma unroll
            for (int n = 0; n < 6; n++) {
                acc[m][n] += lq.x * hv[n].x;
                acc[m][n] += lq.y * hv[n].y;
                acc[m][n] += lq.z * hv[n].z;
                acc[m][n] += lq.w * hv[n].w;
            }
        }
    }

    // butterfly reduce over 64 lanes; lane (m*6+n) owns value (m,n) -> one atomic each
#pragma unroll
    for (int m = 0; m < 8; m++) {
#pragma unroll
        for (int n = 0; n < 6; n++) {
            float v = acc[m][n];
#pragma unroll
            for (int off = 32; off > 0; off >>= 1) v += __shfl_xor(v, off, 64);
            if (l == m * 6 + n)
                atomicAdd(&pooled[(b0 + m) * 96 + colbase + j0 + n], v);
        }
    }
}

// ---------------- MLP head ----------------
__global__ void k_mlp(const float* __restrict__ pooled,
                      const float* __restrict__ fc1w, const float* __restrict__ fc1b,
                      const float* __restrict__ fc2w, const float* __restrict__ fc2b,
                      const float* __restrict__ fc3w, const float* __restrict__ fc3b,
                      float* __restrict__ out) {
    __shared__ float srow[96];
    __shared__ float sh[64];
    __shared__ float sh2[16];
    int b = blockIdx.x, t = threadIdx.x; // 64 threads
    srow[t] = pooled[b * 96 + t];
    if (t < 32) srow[64 + t] = pooled[b * 96 + 64 + t];
    __syncthreads();
    float acc = fc1b[t];
    for (int k = 0; k < 96; k++) acc += srow[k] * fc1w[k * 64 + t];
    sh[t] = fmaxf(acc, 0.0f);
    __syncthreads();
    if (t < 16) {
        float a2 = fc2b[t];
        for (int k = 0; k < 64; k++) a2 += sh[k] * fc2w[k * 16 + t];
        sh2[t] = fmaxf(a2, 0.0f);
    }
    __syncthreads();
    if (t == 0) {
        float a3 = fc3b[0];
        for (int k = 0; k < 16; k++) a3 += sh2[k] * fc3w[k];
        out[b] = a3;
    }
}

extern "C" void kernel_launch(void* const* d_in, const int* in_sizes, int n_in,
                              void* d_out, int out_size, void* d_ws, size_t ws_size,
                              hipStream_t stream) {
    const float* solute_x  = (const float*)d_in[0];
    const float* solvent_x = (const float*)d_in[1];
    const float* su_len    = (const float*)d_in[2];
    const float* sv_len    = (const float*)d_in[3];
    const int*   su_src    = (const int*)d_in[4];
    const int*   su_dst    = (const int*)d_in[5];
    const int*   sv_src    = (const int*)d_in[6];
    const int*   sv_dst    = (const int*)d_in[7];
    const float* W1  = (const float*)d_in[8];
    const float* b1  = (const float*)d_in[9];
    const float* W2  = (const float*)d_in[10];
    const float* b2  = (const float*)d_in[11];
    const float* fc1w = (const float*)d_in[12];
    const float* fc1b = (const float*)d_in[13];
    const float* fc2w = (const float*)d_in[14];
    const float* fc2b = (const float*)d_in[15];
    const float* fc3w = (const float*)d_in[16];
    const float* fc3b = (const float*)d_in[17];
    float* out = (float*)d_out;

    // ---- arena (4B words), total ~77.1 MB ----
    char* ws = (char*)d_ws;
    size_t o = 0;
    auto alloc = [&](size_t elems) { void* p = ws + o * 4; o += elems; return p; };
    int* cnt4     = (int*)alloc((size_t)4 * NBLK * NBINS);  // [D_su][S_su][D_sv][S_sv]
    int* binTot   = (int*)alloc(4 * NBINS);
    int* binBase  = (int*)alloc(4 * (NBINS + 1));
    int* off_su   = (int*)alloc(NN + 1);
    int* off_sv   = (int*)alloc(NN + 1);
    int* csrc_su  = (int*)alloc(NN);
    int* csrc_sv  = (int*)alloc(NN);
    float* pooled = (float*)alloc(NB * 96);
    int* edges_su = (int*)alloc(NE);
    int* edges_sv = (int*)alloc(NE);
    o = (o + 1) & ~(size_t)1;                 // 8B align for int2
    // union region X: build {sortedD int2 NE, sortedS int NE} = 38.4 MB
    //                 compute {ybuf 6.4 + HT_su 19.2 + HT_sv 19.2} = 44.8 MB
    char* X = ws + o * 4;
    int2*   sortedD = (int2*)X;
    int*    sortedS = (int*)(X + (size_t)NE * 8);
    uint_t* ybuf    = (uint_t*)X;
    float*  HT_su   = (float*)(X + (size_t)NN * 64);
    float*  HT_sv   = HT_su + (size_t)NN * 48;

    hipMemsetAsync(binTot, 0, 4 * NBINS * 4, stream);
    hipMemsetAsync(pooled, 0, NB * 96 * 4, stream);

    // ==== phase 1: histograms + scans for BOTH graphs in merged launches ====
    k_p1<<<2 * NBLK, 256, 0, stream>>>(su_src, su_dst, sv_src, sv_dst, cnt4, binTot);
    k_scanA<<<4, 256, 0, stream>>>(binTot, binBase, off_su, off_sv);
    k_scanB<<<4 * NBINS, 256, 0, stream>>>(cnt4, binBase);

    const int* g_src[2]  = {su_src, sv_src};
    const int* g_dst[2]  = {su_dst, sv_dst};
    int* g_off[2]        = {off_su, off_sv};
    int* g_edges[2]      = {edges_su, edges_sv};
    int* g_csrc[2]       = {csrc_su, csrc_sv};

    // per-graph: scatter + counting-sort (sorted buffers reused sequentially)
    for (int g = 0; g < 2; g++) {
        const int* cntD = cnt4 + (size_t)(2 * g) * NBLK * NBINS;
        const int* cntS = cnt4 + (size_t)(2 * g + 1) * NBLK * NBINS;
        const int* bbD  = binBase + (2 * g) * (NBINS + 1);
        const int* bbS  = binBase + (2 * g + 1) * (NBINS + 1);
        k_p3<<<NBLK, 256, 0, stream>>>(g_src[g], g_dst[g], cntD, cntS, sortedD, sortedS);
        k_p4<<<2 * NBINS, 256, 0, stream>>>(sortedD, sortedS, bbD, bbS,
                                            g_off[g], g_edges[g], g_csrc[g]);
    }

    // ==== phase 2: GCN layers (sorted buffers dead; ybuf/HT take over region X) ====
    const float* g_x[2] = {solute_x, solvent_x};
    float* g_HT[2]      = {HT_su, HT_sv};
    for (int g = 0; g < 2; g++) {
        k_t1<<<NN / 8, 256, 0, stream>>>(g_x[g], W1, g_csrc[g], (ushort_t*)ybuf);
        k_agg<32, 1><<<NN / 16, 256, 0, stream>>>(ybuf, g_off[g], g_edges[g], b1, g_HT[g], 0);
        k_t2<<<NN / 16, 256, 0, stream>>>(g_HT[g], W2, g_csrc[g], (ushort_t*)ybuf);
        k_agg<16, 0><<<NN / 32, 256, 0, stream>>>(ybuf, g_off[g], g_edges[g], b2, g_HT[g], 32);
    }

    // ==== pooling + MLP ====
    {
        dim3 gr(NB / 8, NKC, 2);
        k_pool6<<<gr, 512, 0, stream>>>(su_len, sv_len, HT_su, HT_sv, pooled);
    }
    k_mlp<<<NB, 64, 0, stream>>>(pooled, fc1w, fc1b, fc2w, fc2b, fc3w, fc3b, out);
}

// Round 13
// 784.423 us; speedup vs baseline: 1.2258x; 1.0785x over previous
//
#include <hip/hip_runtime.h>
#include <hip/hip_bf16.h>

#define NN 100000
#define NE 3200000
#define NB 512
#define BINW 128                  // nodes per bin (bin = node >> 7)
#define NBINS 782                 // ceil(NN / 128); 782*128 = 100096
#define EPB 8192                  // edges per p1/p3 block
#define NBLK 391                  // ceil(NE / EPB)
#define KCHUNK 6400               // r7-proven; 2048 regressed (epilogue+startup not amortized)
#define NKC 16

typedef unsigned short ushort_t;
typedef unsigned int uint_t;

// async global->LDS, 16B per lane; dest is wave-uniform base + lane*16 (HW rule)
#define GLD_LDS16(gptr, sptr)                                                   \
    __builtin_amdgcn_global_load_lds(                                           \
        (const __attribute__((address_space(1))) void*)(gptr),                  \
        (__attribute__((address_space(3))) void*)(sptr), 16, 0, 0)

// ---------------- p1: per-block bin-histograms (dst AND src), BOTH graphs ----------------
__global__ __launch_bounds__(256) void k_p1(const int* __restrict__ srcA,
                                            const int* __restrict__ dstA,
                                            const int* __restrict__ srcB,
                                            const int* __restrict__ dstB,
                                            int* __restrict__ cnt4,
                                            int* __restrict__ binTot) {
    __shared__ int hD[NBINS], hS[NBINS];
    int t = threadIdx.x, b = blockIdx.x;
    int g = (b >= NBLK) ? 1 : 0;
    int bb = b - g * NBLK;
    const int* src = g ? srcB : srcA;
    const int* dst = g ? dstB : dstA;
    int* cntD = cnt4 + (size_t)(2 * g)     * NBLK * NBINS;
    int* cntS = cnt4 + (size_t)(2 * g + 1) * NBLK * NBINS;
    int* btD  = binTot + (2 * g) * NBINS;
    int* btS  = binTot + (2 * g + 1) * NBINS;
    for (int i = t; i < NBINS; i += 256) { hD[i] = 0; hS[i] = 0; }
    __syncthreads();
    int base = bb * EPB;
#pragma unroll
    for (int i = 0; i < EPB / 1024; i++) {
        int idx = base + i * 1024 + t * 4;
        if (idx < NE) {  // NE%4==0 -> whole int4 valid
            int4 d4 = *(const int4*)(dst + idx);
            int4 s4 = *(const int4*)(src + idx);
            atomicAdd(&hD[d4.x >> 7], 1); atomicAdd(&hD[d4.y >> 7], 1);
            atomicAdd(&hD[d4.z >> 7], 1); atomicAdd(&hD[d4.w >> 7], 1);
            atomicAdd(&hS[s4.x >> 7], 1); atomicAdd(&hS[s4.y >> 7], 1);
            atomicAdd(&hS[s4.z >> 7], 1); atomicAdd(&hS[s4.w >> 7], 1);
        }
    }
    __syncthreads();
    for (int i = t; i < NBINS; i += 256) {
        int vD = hD[i]; cntD[(size_t)bb * NBINS + i] = vD; if (vD) atomicAdd(btD + i, vD);
        int vS = hS[i]; cntS[(size_t)bb * NBINS + i] = vS; if (vS) atomicAdd(btS + i, vS);
    }
}

// ---------------- scanA: exclusive scan of bin totals, 4 units ----------------
__global__ void k_scanA(const int* __restrict__ binTot, int* __restrict__ binBase,
                        int* __restrict__ off_su, int* __restrict__ off_sv) {
    __shared__ int s[NBINS];
    int u = blockIdx.x;  // 0=D_su 1=S_su 2=D_sv 3=S_sv
    const int* bt = binTot + u * NBINS;
    int* bb = binBase + u * (NBINS + 1);
    int t = threadIdx.x;
    for (int i = t; i < NBINS; i += 256) s[i] = bt[i];
    __syncthreads();
    if (t == 0) {
        int acc = 0;
        for (int i = 0; i < NBINS; i++) { int v = s[i]; s[i] = acc; acc += v; }
    }
    __syncthreads();
    for (int i = t; i < NBINS; i += 256) bb[i] = s[i];
    if (t == 0) bb[NBINS] = NE;
    if (t == 0 && u == 0) { off_su[NN] = NE; off_sv[NN] = NE; }
}

// ---------------- scanB: per-bin prefix over blocks, IN PLACE in cnt ----------------
__global__ void k_scanB(int* __restrict__ cnt4, const int* __restrict__ binBase) {
    __shared__ int s[NBLK];
    int u = blockIdx.x / NBINS, j = blockIdx.x % NBINS;
    int* cnt = cnt4 + (size_t)u * NBLK * NBINS;
    const int* bb = binBase + u * (NBINS + 1);
    int t = threadIdx.x;
    for (int i = t; i < NBLK; i += 256) s[i] = cnt[(size_t)i * NBINS + j];
    __syncthreads();
    if (t == 0) {
        int acc = bb[j];
        for (int i = 0; i < NBLK; i++) { int v = s[i]; s[i] = acc; acc += v; }
    }
    __syncthreads();
    for (int i = t; i < NBLK; i += 256) cnt[(size_t)i * NBINS + j] = s[i];
}

// ---------------- p3: dual scatter into bin order (coalesced cursor loads) ----------------
__global__ __launch_bounds__(256) void k_p3(const int* __restrict__ src,
                                            const int* __restrict__ dst,
                                            const int* __restrict__ cntD,
                                            const int* __restrict__ cntS,
                                            int2* __restrict__ sortedD,
                                            int* __restrict__ sortedS) {
    __shared__ int curD[NBINS], curS[NBINS];
    int t = threadIdx.x, b = blockIdx.x;
    for (int i = t; i < NBINS; i += 256) {
        curD[i] = cntD[(size_t)b * NBINS + i];
        curS[i] = cntS[(size_t)b * NBINS + i];
    }
    __syncthreads();
    int base = b * EPB;
#pragma unroll
    for (int i = 0; i < EPB / 1024; i++) {
        int idx = base + i * 1024 + t * 4;
        if (idx < NE) {
            int4 s4 = *(const int4*)(src + idx);
            int4 d4 = *(const int4*)(dst + idx);
            int p;
            p = atomicAdd(&curD[d4.x >> 7], 1); sortedD[p] = make_int2(s4.x, d4.x);
            p = atomicAdd(&curD[d4.y >> 7], 1); sortedD[p] = make_int2(s4.y, d4.y);
            p = atomicAdd(&curD[d4.z >> 7], 1); sortedD[p] = make_int2(s4.z, d4.z);
            p = atomicAdd(&curD[d4.w >> 7], 1); sortedD[p] = make_int2(s4.w, d4.w);
            p = atomicAdd(&curS[s4.x >> 7], 1); sortedS[p] = s4.x;
            p = atomicAdd(&curS[s4.y >> 7], 1); sortedS[p] = s4.y;
            p = atomicAdd(&curS[s4.z >> 7], 1); sortedS[p] = s4.z;
            p = atomicAdd(&curS[s4.w >> 7], 1); sortedS[p] = s4.w;
        }
    }
}

// ---------------- p4 merged: [0,NBINS) counting-sort -> CSR; [NBINS,2N) src-hist ----------------
__global__ __launch_bounds__(256) void k_p4(const int2* __restrict__ sortedD,
                                            const int* __restrict__ sortedS,
                                            const int* __restrict__ bbD,
                                            const int* __restrict__ bbS,
                                            int* __restrict__ off,
                                            int* __restrict__ edges,
                                            int* __restrict__ cnt_src) {
    __shared__ int hist[BINW], pre[BINW], cur[BINW];
    int t = threadIdx.x;
    if (blockIdx.x < NBINS) {
        int bin = blockIdx.x;
        if (t < BINW) hist[t] = 0;
        __syncthreads();
        int e0 = bbD[bin], e1 = bbD[bin + 1];
        for (int e = e0 + t; e < e1; e += 256)
            atomicAdd(&hist[sortedD[e].y & (BINW - 1)], 1);
        __syncthreads();
        if (t == 0) {
            int a = 0;
            for (int i = 0; i < BINW; i++) { pre[i] = a; a += hist[i]; }
        }
        __syncthreads();
        if (t < BINW) {
            cur[t] = pre[t];
            int node = bin * BINW + t;
            if (node < NN) off[node] = e0 + pre[t];
        }
        __syncthreads();
        for (int e = e0 + t; e < e1; e += 256) {
            int2 ed = sortedD[e];
            int p = atomicAdd(&cur[ed.y & (BINW - 1)], 1);
            edges[e0 + p] = ed.x;
        }
    } else {
        int bin = blockIdx.x - NBINS;
        if (t < BINW) hist[t] = 0;
        __syncthreads();
        int e0 = bbS[bin], e1 = bbS[bin + 1];
        for (int e = e0 + t; e < e1; e += 256)
            atomicAdd(&hist[sortedS[e] & (BINW - 1)], 1);
        __syncthreads();
        if (t < BINW) {
            int node = bin * BINW + t;
            if (node < NN) cnt_src[node] = hist[t];
        }
    }
}

// ---------------- t1: y = (x*sn)@W1 (bf16) ----------------
__global__ __launch_bounds__(256) void k_t1(const float* __restrict__ x,
                                            const float* __restrict__ W1,
                                            const int* __restrict__ cnt_src,
                                            ushort_t* __restrict__ y) {
    __shared__ float sW[2048];
    __shared__ float sx[8 * 65];
    int t = threadIdx.x;
    int node0 = blockIdx.x * 8;
    for (int i = t; i < 2048; i += 256) sW[i] = W1[i];
    for (int i = t; i < 512; i += 256) {
        int r = i >> 6, k = i & 63;
        sx[r * 65 + k] = x[(size_t)(node0 + r) * 64 + k];
    }
    __syncthreads();
    int r = t >> 5, c = t & 31;
    int node = node0 + r;
    float sn = rsqrtf(fmaxf((float)cnt_src[node], 1.0f));
    float acc = 0.0f;
#pragma unroll
    for (int k = 0; k < 64; k++) acc += sx[r * 65 + k] * sW[k * 32 + c];
    acc *= sn;   // row scalar commutes with @W1
    __hip_bfloat16 hb = __float2bfloat16(acc);
    y[(size_t)node * 32 + c] = *reinterpret_cast<ushort_t*>(&hb);
}

// ---------------- t2: y2 = (HT_rows(0..31)*sn)@W2 (bf16) ----------------
__global__ __launch_bounds__(256) void k_t2(const float* __restrict__ HT,
                                            const float* __restrict__ W2,
                                            const int* __restrict__ cnt_src,
                                            ushort_t* __restrict__ y2) {
    __shared__ float sW[512];
    __shared__ float sx[16 * 33];
    int t = threadIdx.x;
    int node0 = blockIdx.x * 16;
    for (int i = t; i < 512; i += 256) sW[i] = W2[i];
    for (int i = t; i < 512; i += 256) {
        int r = i & 15, k = i >> 4;  // r fast -> coalesced over node dim
        sx[r * 33 + k] = HT[(size_t)k * NN + node0 + r];
    }
    __syncthreads();
    int r = t >> 4, c = t & 15;
    int node = node0 + r;
    float sn = rsqrtf(fmaxf((float)cnt_src[node], 1.0f));
    float acc = 0.0f;
#pragma unroll
    for (int k = 0; k < 32; k++) acc += sx[r * 33 + k] * sW[k * 16 + c];
    acc *= sn;
    __hip_bfloat16 hb = __float2bfloat16(acc);
    y2[(size_t)node * 16 + c] = *reinterpret_cast<ushort_t*>(&hb);
}

// ---------------- CSR gather aggregation, packed-uint y ----------------
template <int F, int RELU>
__global__ __launch_bounds__(256) void k_agg(
        const uint_t* __restrict__ y, const int* __restrict__ off,
        const int* __restrict__ edges, const float* __restrict__ bias,
        float* __restrict__ HT, int coloff) {
    constexpr int L = F / 2;
    constexpr int NPB = 256 / L;
    int t = threadIdx.x;
    int g = t / L, c2 = t % L;
    int node = blockIdx.x * NPB + g;
    int e0 = off[node], e1 = off[node + 1];
    int deg = e1 - e0;
    const int* srow = edges + e0;
    float a0 = 0.0f, a1 = 0.0f;
    int e = 0;
    for (; e + 3 < deg; e += 4) {
        int s0 = srow[e], s1 = srow[e + 1], s2 = srow[e + 2], s3 = srow[e + 3];
        uint_t u0 = y[(size_t)s0 * L + c2];
        uint_t u1 = y[(size_t)s1 * L + c2];
        uint_t u2 = y[(size_t)s2 * L + c2];
        uint_t u3 = y[(size_t)s3 * L + c2];
        a0 += __uint_as_float(u0 << 16) + __uint_as_float(u1 << 16)
            + __uint_as_float(u2 << 16) + __uint_as_float(u3 << 16);
        a1 += __uint_as_float(u0 & 0xFFFF0000u) + __uint_as_float(u1 & 0xFFFF0000u)
            + __uint_as_float(u2 & 0xFFFF0000u) + __uint_as_float(u3 & 0xFFFF0000u);
    }
    for (; e < deg; e++) {
        uint_t u = y[(size_t)srow[e] * L + c2];
        a0 += __uint_as_float(u << 16);
        a1 += __uint_as_float(u & 0xFFFF0000u);
    }
    float dn = rsqrtf(fmaxf((float)deg, 1.0f));
    float v0 = a0 * dn + bias[2 * c2];
    float v1 = a1 * dn + bias[2 * c2 + 1];
    if (RELU) { v0 = fmaxf(v0, 0.0f); v1 = fmaxf(v1, 0.0f); }
    HT[(size_t)(coloff + 2 * c2) * NN + node] = v0;
    HT[(size_t)(coloff + 2 * c2 + 1) * NN + node] = v1;
}

// ---------------- pooling v7: async-LDS-staged len stream (double buffer) ----------------
// Latency diagnosis (r12): per step, waves did 384 FMA-cycles then stalled ~900 cyc on the
// next step's len HBM loads (VALUBusy 36%). Fix = stage len via global_load_lds into an
// LDS double buffer: next step's 8KB tile (16B/thread, wave-uniform base + lane*16 -- the
// HW-required layout) flies during the current step's FMAs; compute reads lq via
// ds_read_b128 (low latency, lanes stride 16B -> conflict-free). Regs ~90 -> 4 waves/SIMD.
// Tail (last chunk only, 160 elems) stays direct+masked OUTSIDE the staged loop.
// Traffic lesson (pool4->5): all 48 cols of one mat per block (len L1/LDS reuse).
// KCHUNK stays 6400 (r8: 2048 regressed).
__global__ __launch_bounds__(512, 4) void k_pool7(
        const float* __restrict__ lenA, const float* __restrict__ lenB,
        const float* __restrict__ HTA, const float* __restrict__ HTB,
        float* __restrict__ pooled) {
    __shared__ float s_len[2][8][256];
    const int mat = blockIdx.z;
    const float* __restrict__ len = mat ? lenB : lenA;
    const float* __restrict__ HT  = mat ? HTB : HTA;
    const int colbase = mat ? 48 : 0;
    const int b0 = blockIdx.x * 8;
    const int w = threadIdx.x >> 6;      // 0..7: col group for compute, graph for staging
    const int l = threadIdx.x & 63;
    const int j0 = w * 6;

    float acc[8][6];
#pragma unroll
    for (int m = 0; m < 8; m++)
#pragma unroll
        for (int n = 0; n < 6; n++) acc[m][n] = 0.0f;

    const int kc0 = blockIdx.y * KCHUNK;
    const int kc1 = (kc0 + KCHUNK < NN) ? kc0 + KCHUNK : NN;
    const int nfull = (kc1 - kc0) >> 8;        // full 256-wide steps (staged)
    const int rem   = (kc1 - kc0) & 255;       // tail (last chunk only: 160)

    const float* gsrc0 = len + (size_t)(b0 + w) * NN + kc0 + 4 * l;  // staging source
    const float* hp0   = HT + (size_t)j0 * NN + kc0 + 4 * l;         // HT direct

    if (nfull > 0)
        GLD_LDS16(gsrc0, &s_len[0][w][4 * l]);

    int buf = 0;
    for (int s = 0; s < nfull; s++) {
        __syncthreads();  // drains stage(s) (vmcnt) + all waves done reading buf^1
        if (s + 1 < nfull)
            GLD_LDS16(gsrc0 + (s + 1) * 256, &s_len[buf ^ 1][w][4 * l]);
        int koff = s * 256;
        float4 hv[6];
#pragma unroll
        for (int n = 0; n < 6; n++)
            hv[n] = *(const float4*)(hp0 + (size_t)n * NN + koff);
#pragma unroll
        for (int m = 0; m < 8; m++) {
            float4 lq = *(const float4*)(&s_len[buf][m][4 * l]);
#pragma unroll
            for (int n = 0; n < 6; n++) {
                acc[m][n] += lq.x * hv[n].x;
                acc[m][n] += lq.y * hv[n].y;
                acc[m][n] += lq.z * hv[n].z;
                acc[m][n] += lq.w * hv[n].w;
            }
        }
        buf ^= 1;
    }

    if (rem && 4 * l < rem) {  // rem%4==0 -> whole float4 valid for active lanes
        int koff = nfull * 256;
        const float* lp0 = len + (size_t)b0 * NN + kc0 + 4 * l;
        float4 hv[6];
#pragma unroll
        for (int n = 0; n < 6; n++)
            hv[n] = *(const float4*)(hp0 + (size_t)n * NN + koff);
#pragma unroll
        for (int m = 0; m < 8; m++) {
            float4 lq = *(const float4*)(lp0 + (size_t)m * NN + koff);
#pragma unroll
            for (int n = 0; n < 6; n++) {
                acc[m][n] += lq.x * hv[n].x;
                acc[m][n] += lq.y * hv[n].y;
                acc[m][n] += lq.z * hv[n].z;
                acc[m][n] += lq.w * hv[n].w;
            }
        }
    }

    // butterfly reduce over 64 lanes; lane (m*6+n) owns value (m,n) -> one atomic each
#pragma unroll
    for (int m = 0; m < 8; m++) {
#pragma unroll
        for (int n = 0; n < 6; n++) {
            float v = acc[m][n];
#pragma unroll
            for (int off = 32; off > 0; off >>= 1) v += __shfl_xor(v, off, 64);
            if (l == m * 6 + n)
                atomicAdd(&pooled[(b0 + m) * 96 + colbase + j0 + n], v);
        }
    }
}

// ---------------- MLP head ----------------
__global__ void k_mlp(const float* __restrict__ pooled,
                      const float* __restrict__ fc1w, const float* __restrict__ fc1b,
                      const float* __restrict__ fc2w, const float* __restrict__ fc2b,
                      const float* __restrict__ fc3w, const float* __restrict__ fc3b,
                      float* __restrict__ out) {
    __shared__ float srow[96];
    __shared__ float sh[64];
    __shared__ float sh2[16];
    int b = blockIdx.x, t = threadIdx.x; // 64 threads
    srow[t] = pooled[b * 96 + t];
    if (t < 32) srow[64 + t] = pooled[b * 96 + 64 + t];
    __syncthreads();
    float acc = fc1b[t];
    for (int k = 0; k < 96; k++) acc += srow[k] * fc1w[k * 64 + t];
    sh[t] = fmaxf(acc, 0.0f);
    __syncthreads();
    if (t < 16) {
        float a2 = fc2b[t];
        for (int k = 0; k < 64; k++) a2 += sh[k] * fc2w[k * 16 + t];
        sh2[t] = fmaxf(a2, 0.0f);
    }
    __syncthreads();
    if (t == 0) {
        float a3 = fc3b[0];
        for (int k = 0; k < 16; k++) a3 += sh2[k] * fc3w[k];
        out[b] = a3;
    }
}

extern "C" void kernel_launch(void* const* d_in, const int* in_sizes, int n_in,
                              void* d_out, int out_size, void* d_ws, size_t ws_size,
                              hipStream_t stream) {
    const float* solute_x  = (const float*)d_in[0];
    const float* solvent_x = (const float*)d_in[1];
    const float* su_len    = (const float*)d_in[2];
    const float* sv_len    = (const float*)d_in[3];
    const int*   su_src    = (const int*)d_in[4];
    const int*   su_dst    = (const int*)d_in[5];
    const int*   sv_src    = (const int*)d_in[6];
    const int*   sv_dst    = (const int*)d_in[7];
    const float* W1  = (const float*)d_in[8];
    const float* b1  = (const float*)d_in[9];
    const float* W2  = (const float*)d_in[10];
    const float* b2  = (const float*)d_in[11];
    const float* fc1w = (const float*)d_in[12];
    const float* fc1b = (const float*)d_in[13];
    const float* fc2w = (const float*)d_in[14];
    const float* fc2b = (const float*)d_in[15];
    const float* fc3w = (const float*)d_in[16];
    const float* fc3b = (const float*)d_in[17];
    float* out = (float*)d_out;

    // ---- arena (4B words), total ~77.1 MB ----
    char* ws = (char*)d_ws;
    size_t o = 0;
    auto alloc = [&](size_t elems) { void* p = ws + o * 4; o += elems; return p; };
    int* cnt4     = (int*)alloc((size_t)4 * NBLK * NBINS);  // [D_su][S_su][D_sv][S_sv]
    int* binTot   = (int*)alloc(4 * NBINS);
    int* binBase  = (int*)alloc(4 * (NBINS + 1));
    int* off_su   = (int*)alloc(NN + 1);
    int* off_sv   = (int*)alloc(NN + 1);
    int* csrc_su  = (int*)alloc(NN);
    int* csrc_sv  = (int*)alloc(NN);
    float* pooled = (float*)alloc(NB * 96);
    int* edges_su = (int*)alloc(NE);
    int* edges_sv = (int*)alloc(NE);
    o = (o + 1) & ~(size_t)1;                 // 8B align for int2
    // union region X: build {sortedD int2 NE, sortedS int NE} = 38.4 MB
    //                 compute {ybuf 6.4 + HT_su 19.2 + HT_sv 19.2} = 44.8 MB
    char* X = ws + o * 4;
    int2*   sortedD = (int2*)X;
    int*    sortedS = (int*)(X + (size_t)NE * 8);
    uint_t* ybuf    = (uint_t*)X;
    float*  HT_su   = (float*)(X + (size_t)NN * 64);
    float*  HT_sv   = HT_su + (size_t)NN * 48;

    hipMemsetAsync(binTot, 0, 4 * NBINS * 4, stream);
    hipMemsetAsync(pooled, 0, NB * 96 * 4, stream);

    // ==== phase 1: histograms + scans for BOTH graphs in merged launches ====
    k_p1<<<2 * NBLK, 256, 0, stream>>>(su_src, su_dst, sv_src, sv_dst, cnt4, binTot);
    k_scanA<<<4, 256, 0, stream>>>(binTot, binBase, off_su, off_sv);
    k_scanB<<<4 * NBINS, 256, 0, stream>>>(cnt4, binBase);

    const int* g_src[2]  = {su_src, sv_src};
    const int* g_dst[2]  = {su_dst, sv_dst};
    int* g_off[2]        = {off_su, off_sv};
    int* g_edges[2]      = {edges_su, edges_sv};
    int* g_csrc[2]       = {csrc_su, csrc_sv};

    // per-graph: scatter + counting-sort (sorted buffers reused sequentially)
    for (int g = 0; g < 2; g++) {
        const int* cntD = cnt4 + (size_t)(2 * g) * NBLK * NBINS;
        const int* cntS = cnt4 + (size_t)(2 * g + 1) * NBLK * NBINS;
        const int* bbD  = binBase + (2 * g) * (NBINS + 1);
        const int* bbS  = binBase + (2 * g + 1) * (NBINS + 1);
        k_p3<<<NBLK, 256, 0, stream>>>(g_src[g], g_dst[g], cntD, cntS, sortedD, sortedS);
        k_p4<<<2 * NBINS, 256, 0, stream>>>(sortedD, sortedS, bbD, bbS,
                                            g_off[g], g_edges[g], g_csrc[g]);
    }

    // ==== phase 2: GCN layers (sorted buffers dead; ybuf/HT take over region X) ====
    const float* g_x[2] = {solute_x, solvent_x};
    float* g_HT[2]      = {HT_su, HT_sv};
    for (int g = 0; g < 2; g++) {
        k_t1<<<NN / 8, 256, 0, stream>>>(g_x[g], W1, g_csrc[g], (ushort_t*)ybuf);
        k_agg<32, 1><<<NN / 16, 256, 0, stream>>>(ybuf, g_off[g], g_edges[g], b1, g_HT[g], 0);
        k_t2<<<NN / 16, 256, 0, stream>>>(g_HT[g], W2, g_csrc[g], (ushort_t*)ybuf);
        k_agg<16, 0><<<NN / 32, 256, 0, stream>>>(ybuf, g_off[g], g_edges[g], b2, g_HT[g], 32);
    }

    // ==== pooling + MLP ====
    {
        dim3 gr(NB / 8, NKC, 2);
        k_pool7<<<gr, 512, 0, stream>>>(su_len, sv_len, HT_su, HT_sv, pooled);
    }
    k_mlp<<<NB, 64, 0, stream>>>(pooled, fc1w, fc1b, fc2w, fc2b, fc3w, fc3b, out);
}

// Round 14
// 780.586 us; speedup vs baseline: 1.2318x; 1.0049x over previous
//
#include <hip/hip_runtime.h>
#include <hip/hip_bf16.h>

#define NN 100000
#define NE 3200000
#define NB 512
#define BINW 128                  // nodes per bin (bin = node >> 7)
#define NBINS 782                 // ceil(NN / 128); 782*128 = 100096
#define EPB 8192                  // edges per p1/p3 block
#define NBLK 391                  // ceil(NE / EPB)
#define KCHUNK 6400               // r7-proven; 2048 regressed (epilogue+startup not amortized)
#define NKC 16

typedef unsigned short ushort_t;
typedef unsigned int uint_t;

// async global->LDS, 16B per lane; dest is wave-uniform base + lane*16 (HW rule)
#define GLD_LDS16(gptr, sptr)                                                   \
    __builtin_amdgcn_global_load_lds(                                           \
        (const __attribute__((address_space(1))) void*)(gptr),                  \
        (__attribute__((address_space(3))) void*)(sptr), 16, 0, 0)

// ---------------- p1: per-block bin-histograms (dst AND src), BOTH graphs ----------------
__global__ __launch_bounds__(256) void k_p1(const int* __restrict__ srcA,
                                            const int* __restrict__ dstA,
                                            const int* __restrict__ srcB,
                                            const int* __restrict__ dstB,
                                            int* __restrict__ cnt4,
                                            int* __restrict__ binTot) {
    __shared__ int hD[NBINS], hS[NBINS];
    int t = threadIdx.x, b = blockIdx.x;
    int g = (b >= NBLK) ? 1 : 0;
    int bb = b - g * NBLK;
    const int* src = g ? srcB : srcA;
    const int* dst = g ? dstB : dstA;
    int* cntD = cnt4 + (size_t)(2 * g)     * NBLK * NBINS;
    int* cntS = cnt4 + (size_t)(2 * g + 1) * NBLK * NBINS;
    int* btD  = binTot + (2 * g) * NBINS;
    int* btS  = binTot + (2 * g + 1) * NBINS;
    for (int i = t; i < NBINS; i += 256) { hD[i] = 0; hS[i] = 0; }
    __syncthreads();
    int base = bb * EPB;
#pragma unroll
    for (int i = 0; i < EPB / 1024; i++) {
        int idx = base + i * 1024 + t * 4;
        if (idx < NE) {  // NE%4==0 -> whole int4 valid
            int4 d4 = *(const int4*)(dst + idx);
            int4 s4 = *(const int4*)(src + idx);
            atomicAdd(&hD[d4.x >> 7], 1); atomicAdd(&hD[d4.y >> 7], 1);
            atomicAdd(&hD[d4.z >> 7], 1); atomicAdd(&hD[d4.w >> 7], 1);
            atomicAdd(&hS[s4.x >> 7], 1); atomicAdd(&hS[s4.y >> 7], 1);
            atomicAdd(&hS[s4.z >> 7], 1); atomicAdd(&hS[s4.w >> 7], 1);
        }
    }
    __syncthreads();
    for (int i = t; i < NBINS; i += 256) {
        int vD = hD[i]; cntD[(size_t)bb * NBINS + i] = vD; if (vD) atomicAdd(btD + i, vD);
        int vS = hS[i]; cntS[(size_t)bb * NBINS + i] = vS; if (vS) atomicAdd(btS + i, vS);
    }
}

// ---------------- scanA: exclusive scan of bin totals, 4 units ----------------
__global__ void k_scanA(const int* __restrict__ binTot, int* __restrict__ binBase,
                        int* __restrict__ off_su, int* __restrict__ off_sv) {
    __shared__ int s[NBINS];
    int u = blockIdx.x;  // 0=D_su 1=S_su 2=D_sv 3=S_sv
    const int* bt = binTot + u * NBINS;
    int* bb = binBase + u * (NBINS + 1);
    int t = threadIdx.x;
    for (int i = t; i < NBINS; i += 256) s[i] = bt[i];
    __syncthreads();
    if (t == 0) {
        int acc = 0;
        for (int i = 0; i < NBINS; i++) { int v = s[i]; s[i] = acc; acc += v; }
    }
    __syncthreads();
    for (int i = t; i < NBINS; i += 256) bb[i] = s[i];
    if (t == 0) bb[NBINS] = NE;
    if (t == 0 && u == 0) { off_su[NN] = NE; off_sv[NN] = NE; }
}

// ---------------- scanB: per-bin prefix over blocks, IN PLACE in cnt ----------------
__global__ void k_scanB(int* __restrict__ cnt4, const int* __restrict__ binBase) {
    __shared__ int s[NBLK];
    int u = blockIdx.x / NBINS, j = blockIdx.x % NBINS;
    int* cnt = cnt4 + (size_t)u * NBLK * NBINS;
    const int* bb = binBase + u * (NBINS + 1);
    int t = threadIdx.x;
    for (int i = t; i < NBLK; i += 256) s[i] = cnt[(size_t)i * NBINS + j];
    __syncthreads();
    if (t == 0) {
        int acc = bb[j];
        for (int i = 0; i < NBLK; i++) { int v = s[i]; s[i] = acc; acc += v; }
    }
    __syncthreads();
    for (int i = t; i < NBLK; i += 256) cnt[(size_t)i * NBINS + j] = s[i];
}

// ---------------- p3: dual scatter into bin order (coalesced cursor loads) ----------------
__global__ __launch_bounds__(256) void k_p3(const int* __restrict__ src,
                                            const int* __restrict__ dst,
                                            const int* __restrict__ cntD,
                                            const int* __restrict__ cntS,
                                            int2* __restrict__ sortedD,
                                            int* __restrict__ sortedS) {
    __shared__ int curD[NBINS], curS[NBINS];
    int t = threadIdx.x, b = blockIdx.x;
    for (int i = t; i < NBINS; i += 256) {
        curD[i] = cntD[(size_t)b * NBINS + i];
        curS[i] = cntS[(size_t)b * NBINS + i];
    }
    __syncthreads();
    int base = b * EPB;
#pragma unroll
    for (int i = 0; i < EPB / 1024; i++) {
        int idx = base + i * 1024 + t * 4;
        if (idx < NE) {
            int4 s4 = *(const int4*)(src + idx);
            int4 d4 = *(const int4*)(dst + idx);
            int p;
            p = atomicAdd(&curD[d4.x >> 7], 1); sortedD[p] = make_int2(s4.x, d4.x);
            p = atomicAdd(&curD[d4.y >> 7], 1); sortedD[p] = make_int2(s4.y, d4.y);
            p = atomicAdd(&curD[d4.z >> 7], 1); sortedD[p] = make_int2(s4.z, d4.z);
            p = atomicAdd(&curD[d4.w >> 7], 1); sortedD[p] = make_int2(s4.w, d4.w);
            p = atomicAdd(&curS[s4.x >> 7], 1); sortedS[p] = s4.x;
            p = atomicAdd(&curS[s4.y >> 7], 1); sortedS[p] = s4.y;
            p = atomicAdd(&curS[s4.z >> 7], 1); sortedS[p] = s4.z;
            p = atomicAdd(&curS[s4.w >> 7], 1); sortedS[p] = s4.w;
        }
    }
}

// ---------------- p4 merged: [0,NBINS) counting-sort -> CSR; [NBINS,2N) src-hist ----------------
__global__ __launch_bounds__(256) void k_p4(const int2* __restrict__ sortedD,
                                            const int* __restrict__ sortedS,
                                            const int* __restrict__ bbD,
                                            const int* __restrict__ bbS,
                                            int* __restrict__ off,
                                            int* __restrict__ edges,
                                            int* __restrict__ cnt_src) {
    __shared__ int hist[BINW], pre[BINW], cur[BINW];
    int t = threadIdx.x;
    if (blockIdx.x < NBINS) {
        int bin = blockIdx.x;
        if (t < BINW) hist[t] = 0;
        __syncthreads();
        int e0 = bbD[bin], e1 = bbD[bin + 1];
        for (int e = e0 + t; e < e1; e += 256)
            atomicAdd(&hist[sortedD[e].y & (BINW - 1)], 1);
        __syncthreads();
        if (t == 0) {
            int a = 0;
            for (int i = 0; i < BINW; i++) { pre[i] = a; a += hist[i]; }
        }
        __syncthreads();
        if (t < BINW) {
            cur[t] = pre[t];
            int node = bin * BINW + t;
            if (node < NN) off[node] = e0 + pre[t];
        }
        __syncthreads();
        for (int e = e0 + t; e < e1; e += 256) {
            int2 ed = sortedD[e];
            int p = atomicAdd(&cur[ed.y & (BINW - 1)], 1);
            edges[e0 + p] = ed.x;
        }
    } else {
        int bin = blockIdx.x - NBINS;
        if (t < BINW) hist[t] = 0;
        __syncthreads();
        int e0 = bbS[bin], e1 = bbS[bin + 1];
        for (int e = e0 + t; e < e1; e += 256)
            atomicAdd(&hist[sortedS[e] & (BINW - 1)], 1);
        __syncthreads();
        if (t < BINW) {
            int node = bin * BINW + t;
            if (node < NN) cnt_src[node] = hist[t];
        }
    }
}

// ---------------- t1: y = (x*sn)@W1 (bf16) ----------------
__global__ __launch_bounds__(256) void k_t1(const float* __restrict__ x,
                                            const float* __restrict__ W1,
                                            const int* __restrict__ cnt_src,
                                            ushort_t* __restrict__ y) {
    __shared__ float sW[2048];
    __shared__ float sx[8 * 65];
    int t = threadIdx.x;
    int node0 = blockIdx.x * 8;
    for (int i = t; i < 2048; i += 256) sW[i] = W1[i];
    for (int i = t; i < 512; i += 256) {
        int r = i >> 6, k = i & 63;
        sx[r * 65 + k] = x[(size_t)(node0 + r) * 64 + k];
    }
    __syncthreads();
    int r = t >> 5, c = t & 31;
    int node = node0 + r;
    float sn = rsqrtf(fmaxf((float)cnt_src[node], 1.0f));
    float acc = 0.0f;
#pragma unroll
    for (int k = 0; k < 64; k++) acc += sx[r * 65 + k] * sW[k * 32 + c];
    acc *= sn;   // row scalar commutes with @W1
    __hip_bfloat16 hb = __float2bfloat16(acc);
    y[(size_t)node * 32 + c] = *reinterpret_cast<ushort_t*>(&hb);
}

// ---------------- t2: y2 = (HT_rows(0..31)*sn)@W2 (bf16) ----------------
__global__ __launch_bounds__(256) void k_t2(const float* __restrict__ HT,
                                            const float* __restrict__ W2,
                                            const int* __restrict__ cnt_src,
                                            ushort_t* __restrict__ y2) {
    __shared__ float sW[512];
    __shared__ float sx[16 * 33];
    int t = threadIdx.x;
    int node0 = blockIdx.x * 16;
    for (int i = t; i < 512; i += 256) sW[i] = W2[i];
    for (int i = t; i < 512; i += 256) {
        int r = i & 15, k = i >> 4;  // r fast -> coalesced over node dim
        sx[r * 33 + k] = HT[(size_t)k * NN + node0 + r];
    }
    __syncthreads();
    int r = t >> 4, c = t & 15;
    int node = node0 + r;
    float sn = rsqrtf(fmaxf((float)cnt_src[node], 1.0f));
    float acc = 0.0f;
#pragma unroll
    for (int k = 0; k < 32; k++) acc += sx[r * 33 + k] * sW[k * 16 + c];
    acc *= sn;
    __hip_bfloat16 hb = __float2bfloat16(acc);
    y2[(size_t)node * 16 + c] = *reinterpret_cast<ushort_t*>(&hb);
}

// ---------------- CSR gather aggregation, packed-uint y ----------------
template <int F, int RELU>
__global__ __launch_bounds__(256) void k_agg(
        const uint_t* __restrict__ y, const int* __restrict__ off,
        const int* __restrict__ edges, const float* __restrict__ bias,
        float* __restrict__ HT, int coloff) {
    constexpr int L = F / 2;
    constexpr int NPB = 256 / L;
    int t = threadIdx.x;
    int g = t / L, c2 = t % L;
    int node = blockIdx.x * NPB + g;
    int e0 = off[node], e1 = off[node + 1];
    int deg = e1 - e0;
    const int* srow = edges + e0;
    float a0 = 0.0f, a1 = 0.0f;
    int e = 0;
    for (; e + 3 < deg; e += 4) {
        int s0 = srow[e], s1 = srow[e + 1], s2 = srow[e + 2], s3 = srow[e + 3];
        uint_t u0 = y[(size_t)s0 * L + c2];
        uint_t u1 = y[(size_t)s1 * L + c2];
        uint_t u2 = y[(size_t)s2 * L + c2];
        uint_t u3 = y[(size_t)s3 * L + c2];
        a0 += __uint_as_float(u0 << 16) + __uint_as_float(u1 << 16)
            + __uint_as_float(u2 << 16) + __uint_as_float(u3 << 16);
        a1 += __uint_as_float(u0 & 0xFFFF0000u) + __uint_as_float(u1 & 0xFFFF0000u)
            + __uint_as_float(u2 & 0xFFFF0000u) + __uint_as_float(u3 & 0xFFFF0000u);
    }
    for (; e < deg; e++) {
        uint_t u = y[(size_t)srow[e] * L + c2];
        a0 += __uint_as_float(u << 16);
        a1 += __uint_as_float(u & 0xFFFF0000u);
    }
    float dn = rsqrtf(fmaxf((float)deg, 1.0f));
    float v0 = a0 * dn + bias[2 * c2];
    float v1 = a1 * dn + bias[2 * c2 + 1];
    if (RELU) { v0 = fmaxf(v0, 0.0f); v1 = fmaxf(v1, 0.0f); }
    HT[(size_t)(coloff + 2 * c2) * NN + node] = v0;
    HT[(size_t)(coloff + 2 * c2 + 1) * NN + node] = v1;
}

// ---------------- pooling v8: LDS-staged len + register-prefetched HT ----------------
// r13 result: len staging got VALUBusy 36->41% but the 6 hv (HT) loads are issued at the
// top of each step and consumed immediately -> each step exposes ~300-500cyc of L2 latency
// (the vmcnt(0) drain at __syncthreads prevents cross-barrier flight). Fix: register
// double-buffer hv -- issue step s+1's HT loads right after the stage call, BEFORE the
// FMA block; their latency hides under the 384-cycle FMA phase and they land by the
// barrier drain. +24 VGPR (~112 total) still fits 4 waves/SIMD.
// Invariants: all 48 cols per block (len reuse); KCHUNK 6400; tail outside staged loop.
__global__ __launch_bounds__(512, 4) void k_pool8(
        const float* __restrict__ lenA, const float* __restrict__ lenB,
        const float* __restrict__ HTA, const float* __restrict__ HTB,
        float* __restrict__ pooled) {
    __shared__ float s_len[2][8][256];
    const int mat = blockIdx.z;
    const float* __restrict__ len = mat ? lenB : lenA;
    const float* __restrict__ HT  = mat ? HTB : HTA;
    const int colbase = mat ? 48 : 0;
    const int b0 = blockIdx.x * 8;
    const int w = threadIdx.x >> 6;      // 0..7: col group for compute, graph for staging
    const int l = threadIdx.x & 63;
    const int j0 = w * 6;

    float acc[8][6];
#pragma unroll
    for (int m = 0; m < 8; m++)
#pragma unroll
        for (int n = 0; n < 6; n++) acc[m][n] = 0.0f;

    const int kc0 = blockIdx.y * KCHUNK;
    const int kc1 = (kc0 + KCHUNK < NN) ? kc0 + KCHUNK : NN;
    const int nfull = (kc1 - kc0) >> 8;        // full 256-wide steps (staged)
    const int rem   = (kc1 - kc0) & 255;       // tail (last chunk only: 160)

    const float* gsrc0 = len + (size_t)(b0 + w) * NN + kc0 + 4 * l;  // len staging source
    const float* hp0   = HT + (size_t)j0 * NN + kc0 + 4 * l;         // HT direct

    float4 hv[6];
    if (nfull > 0) {
        GLD_LDS16(gsrc0, &s_len[0][w][4 * l]);
#pragma unroll
        for (int n = 0; n < 6; n++)
            hv[n] = *(const float4*)(hp0 + (size_t)n * NN);
    }

    int buf = 0;
    for (int s = 0; s < nfull; s++) {
        __syncthreads();  // len stage for step s has landed; all waves done with buf^1
        if (s + 1 < nfull)
            GLD_LDS16(gsrc0 + (s + 1) * 256, &s_len[buf ^ 1][w][4 * l]);
        // prefetch next step's HT into registers (clamped on last step -> redundant reload)
        int knext = (s + 1 < nfull) ? (s + 1) * 256 : s * 256;
        float4 hvn[6];
#pragma unroll
        for (int n = 0; n < 6; n++)
            hvn[n] = *(const float4*)(hp0 + (size_t)n * NN + knext);
        // compute step s from LDS len + registered hv
#pragma unroll
        for (int m = 0; m < 8; m++) {
            float4 lq = *(const float4*)(&s_len[buf][m][4 * l]);
#pragma unroll
            for (int n = 0; n < 6; n++) {
                acc[m][n] += lq.x * hv[n].x;
                acc[m][n] += lq.y * hv[n].y;
                acc[m][n] += lq.z * hv[n].z;
                acc[m][n] += lq.w * hv[n].w;
            }
        }
#pragma unroll
        for (int n = 0; n < 6; n++) hv[n] = hvn[n];
        buf ^= 1;
    }

    if (rem && 4 * l < rem) {  // rem%4==0 -> whole float4 valid for active lanes
        int koff = nfull * 256;
        const float* lp0 = len + (size_t)b0 * NN + kc0 + 4 * l;
        float4 hvt[6];
#pragma unroll
        for (int n = 0; n < 6; n++)
            hvt[n] = *(const float4*)(hp0 + (size_t)n * NN + koff);
#pragma unroll
        for (int m = 0; m < 8; m++) {
            float4 lq = *(const float4*)(lp0 + (size_t)m * NN + koff);
#pragma unroll
            for (int n = 0; n < 6; n++) {
                acc[m][n] += lq.x * hvt[n].x;
                acc[m][n] += lq.y * hvt[n].y;
                acc[m][n] += lq.z * hvt[n].z;
                acc[m][n] += lq.w * hvt[n].w;
            }
        }
    }

    // butterfly reduce over 64 lanes; lane (m*6+n) owns value (m,n) -> one atomic each
#pragma unroll
    for (int m = 0; m < 8; m++) {
#pragma unroll
        for (int n = 0; n < 6; n++) {
            float v = acc[m][n];
#pragma unroll
            for (int off = 32; off > 0; off >>= 1) v += __shfl_xor(v, off, 64);
            if (l == m * 6 + n)
                atomicAdd(&pooled[(b0 + m) * 96 + colbase + j0 + n], v);
        }
    }
}

// ---------------- MLP head ----------------
__global__ void k_mlp(const float* __restrict__ pooled,
                      const float* __restrict__ fc1w, const float* __restrict__ fc1b,
                      const float* __restrict__ fc2w, const float* __restrict__ fc2b,
                      const float* __restrict__ fc3w, const float* __restrict__ fc3b,
                      float* __restrict__ out) {
    __shared__ float srow[96];
    __shared__ float sh[64];
    __shared__ float sh2[16];
    int b = blockIdx.x, t = threadIdx.x; // 64 threads
    srow[t] = pooled[b * 96 + t];
    if (t < 32) srow[64 + t] = pooled[b * 96 + 64 + t];
    __syncthreads();
    float acc = fc1b[t];
    for (int k = 0; k < 96; k++) acc += srow[k] * fc1w[k * 64 + t];
    sh[t] = fmaxf(acc, 0.0f);
    __syncthreads();
    if (t < 16) {
        float a2 = fc2b[t];
        for (int k = 0; k < 64; k++) a2 += sh[k] * fc2w[k * 16 + t];
        sh2[t] = fmaxf(a2, 0.0f);
    }
    __syncthreads();
    if (t == 0) {
        float a3 = fc3b[0];
        for (int k = 0; k < 16; k++) a3 += sh2[k] * fc3w[k];
        out[b] = a3;
    }
}

extern "C" void kernel_launch(void* const* d_in, const int* in_sizes, int n_in,
                              void* d_out, int out_size, void* d_ws, size_t ws_size,
                              hipStream_t stream) {
    const float* solute_x  = (const float*)d_in[0];
    const float* solvent_x = (const float*)d_in[1];
    const float* su_len    = (const float*)d_in[2];
    const float* sv_len    = (const float*)d_in[3];
    const int*   su_src    = (const int*)d_in[4];
    const int*   su_dst    = (const int*)d_in[5];
    const int*   sv_src    = (const int*)d_in[6];
    const int*   sv_dst    = (const int*)d_in[7];
    const float* W1  = (const float*)d_in[8];
    const float* b1  = (const float*)d_in[9];
    const float* W2  = (const float*)d_in[10];
    const float* b2  = (const float*)d_in[11];
    const float* fc1w = (const float*)d_in[12];
    const float* fc1b = (const float*)d_in[13];
    const float* fc2w = (const float*)d_in[14];
    const float* fc2b = (const float*)d_in[15];
    const float* fc3w = (const float*)d_in[16];
    const float* fc3b = (const float*)d_in[17];
    float* out = (float*)d_out;

    // ---- arena (4B words), total ~77.1 MB ----
    char* ws = (char*)d_ws;
    size_t o = 0;
    auto alloc = [&](size_t elems) { void* p = ws + o * 4; o += elems; return p; };
    int* cnt4     = (int*)alloc((size_t)4 * NBLK * NBINS);  // [D_su][S_su][D_sv][S_sv]
    int* binTot   = (int*)alloc(4 * NBINS);
    int* binBase  = (int*)alloc(4 * (NBINS + 1));
    int* off_su   = (int*)alloc(NN + 1);
    int* off_sv   = (int*)alloc(NN + 1);
    int* csrc_su  = (int*)alloc(NN);
    int* csrc_sv  = (int*)alloc(NN);
    float* pooled = (float*)alloc(NB * 96);
    int* edges_su = (int*)alloc(NE);
    int* edges_sv = (int*)alloc(NE);
    o = (o + 1) & ~(size_t)1;                 // 8B align for int2
    // union region X: build {sortedD int2 NE, sortedS int NE} = 38.4 MB
    //                 compute {ybuf 6.4 + HT_su 19.2 + HT_sv 19.2} = 44.8 MB
    char* X = ws + o * 4;
    int2*   sortedD = (int2*)X;
    int*    sortedS = (int*)(X + (size_t)NE * 8);
    uint_t* ybuf    = (uint_t*)X;
    float*  HT_su   = (float*)(X + (size_t)NN * 64);
    float*  HT_sv   = HT_su + (size_t)NN * 48;

    hipMemsetAsync(binTot, 0, 4 * NBINS * 4, stream);
    hipMemsetAsync(pooled, 0, NB * 96 * 4, stream);

    // ==== phase 1: histograms + scans for BOTH graphs in merged launches ====
    k_p1<<<2 * NBLK, 256, 0, stream>>>(su_src, su_dst, sv_src, sv_dst, cnt4, binTot);
    k_scanA<<<4, 256, 0, stream>>>(binTot, binBase, off_su, off_sv);
    k_scanB<<<4 * NBINS, 256, 0, stream>>>(cnt4, binBase);

    const int* g_src[2]  = {su_src, sv_src};
    const int* g_dst[2]  = {su_dst, sv_dst};
    int* g_off[2]        = {off_su, off_sv};
    int* g_edges[2]      = {edges_su, edges_sv};
    int* g_csrc[2]       = {csrc_su, csrc_sv};

    // per-graph: scatter + counting-sort (sorted buffers reused sequentially)
    for (int g = 0; g < 2; g++) {
        const int* cntD = cnt4 + (size_t)(2 * g) * NBLK * NBINS;
        const int* cntS = cnt4 + (size_t)(2 * g + 1) * NBLK * NBINS;
        const int* bbD  = binBase + (2 * g) * (NBINS + 1);
        const int* bbS  = binBase + (2 * g + 1) * (NBINS + 1);
        k_p3<<<NBLK, 256, 0, stream>>>(g_src[g], g_dst[g], cntD, cntS, sortedD, sortedS);
        k_p4<<<2 * NBINS, 256, 0, stream>>>(sortedD, sortedS, bbD, bbS,
                                            g_off[g], g_edges[g], g_csrc[g]);
    }

    // ==== phase 2: GCN layers (sorted buffers dead; ybuf/HT take over region X) ====
    const float* g_x[2] = {solute_x, solvent_x};
    float* g_HT[2]      = {HT_su, HT_sv};
    for (int g = 0; g < 2; g++) {
        k_t1<<<NN / 8, 256, 0, stream>>>(g_x[g], W1, g_csrc[g], (ushort_t*)ybuf);
        k_agg<32, 1><<<NN / 16, 256, 0, stream>>>(ybuf, g_off[g], g_edges[g], b1, g_HT[g], 0);
        k_t2<<<NN / 16, 256, 0, stream>>>(g_HT[g], W2, g_csrc[g], (ushort_t*)ybuf);
        k_agg<16, 0><<<NN / 32, 256, 0, stream>>>(ybuf, g_off[g], g_edges[g], b2, g_HT[g], 32);
    }

    // ==== pooling + MLP ====
    {
        dim3 gr(NB / 8, NKC, 2);
        k_pool8<<<gr, 512, 0, stream>>>(su_len, sv_len, HT_su, HT_sv, pooled);
    }
    k_mlp<<<NB, 64, 0, stream>>>(pooled, fc1w, fc1b, fc2w, fc2b, fc3w, fc3b, out);
}

// Round 15
// 736.262 us; speedup vs baseline: 1.3060x; 1.0602x over previous
//
#include <hip/hip_runtime.h>
#include <hip/hip_bf16.h>

#define NN 100000
#define NE 3200000
#define NB 512
#define BINW 128                  // nodes per bin (bin = node >> 7)
#define NBINS 782                 // ceil(NN / 128); 782*128 = 100096
#define EPB 8192                  // edges per p1/p3 block
#define NBLK 391                  // ceil(NE / EPB)
#define PK 12544                  // pool k-chunk (multiple of 128; 8*12544 = 100352 >= NN)
#define PNK 8

typedef unsigned short ushort_t;
typedef unsigned int uint_t;
typedef __attribute__((ext_vector_type(8))) short short8v;   // 8 bf16 (4 VGPRs)
typedef __attribute__((ext_vector_type(4))) float f32x4v;

static __device__ __forceinline__ short f2bf(float f) {
    __hip_bfloat16 h = __float2bfloat16(f);
    return *reinterpret_cast<short*>(&h);
}
static __device__ __forceinline__ float bf2f(ushort_t u) {
    return __uint_as_float(((uint_t)u) << 16);
}

// ---------------- p1: per-block bin-histograms (dst AND src), BOTH graphs ----------------
__global__ __launch_bounds__(256) void k_p1(const int* __restrict__ srcA,
                                            const int* __restrict__ dstA,
                                            const int* __restrict__ srcB,
                                            const int* __restrict__ dstB,
                                            int* __restrict__ cnt4,
                                            int* __restrict__ binTot) {
    __shared__ int hD[NBINS], hS[NBINS];
    int t = threadIdx.x, b = blockIdx.x;
    int g = (b >= NBLK) ? 1 : 0;
    int bb = b - g * NBLK;
    const int* src = g ? srcB : srcA;
    const int* dst = g ? dstB : dstA;
    int* cntD = cnt4 + (size_t)(2 * g)     * NBLK * NBINS;
    int* cntS = cnt4 + (size_t)(2 * g + 1) * NBLK * NBINS;
    int* btD  = binTot + (2 * g) * NBINS;
    int* btS  = binTot + (2 * g + 1) * NBINS;
    for (int i = t; i < NBINS; i += 256) { hD[i] = 0; hS[i] = 0; }
    __syncthreads();
    int base = bb * EPB;
#pragma unroll
    for (int i = 0; i < EPB / 1024; i++) {
        int idx = base + i * 1024 + t * 4;
        if (idx < NE) {  // NE%4==0 -> whole int4 valid
            int4 d4 = *(const int4*)(dst + idx);
            int4 s4 = *(const int4*)(src + idx);
            atomicAdd(&hD[d4.x >> 7], 1); atomicAdd(&hD[d4.y >> 7], 1);
            atomicAdd(&hD[d4.z >> 7], 1); atomicAdd(&hD[d4.w >> 7], 1);
            atomicAdd(&hS[s4.x >> 7], 1); atomicAdd(&hS[s4.y >> 7], 1);
            atomicAdd(&hS[s4.z >> 7], 1); atomicAdd(&hS[s4.w >> 7], 1);
        }
    }
    __syncthreads();
    for (int i = t; i < NBINS; i += 256) {
        int vD = hD[i]; cntD[(size_t)bb * NBINS + i] = vD; if (vD) atomicAdd(btD + i, vD);
        int vS = hS[i]; cntS[(size_t)bb * NBINS + i] = vS; if (vS) atomicAdd(btS + i, vS);
    }
}

// ---------------- scanA: exclusive scan of bin totals, 4 units ----------------
__global__ void k_scanA(const int* __restrict__ binTot, int* __restrict__ binBase,
                        int* __restrict__ off_su, int* __restrict__ off_sv) {
    __shared__ int s[NBINS];
    int u = blockIdx.x;  // 0=D_su 1=S_su 2=D_sv 3=S_sv
    const int* bt = binTot + u * NBINS;
    int* bb = binBase + u * (NBINS + 1);
    int t = threadIdx.x;
    for (int i = t; i < NBINS; i += 256) s[i] = bt[i];
    __syncthreads();
    if (t == 0) {
        int acc = 0;
        for (int i = 0; i < NBINS; i++) { int v = s[i]; s[i] = acc; acc += v; }
    }
    __syncthreads();
    for (int i = t; i < NBINS; i += 256) bb[i] = s[i];
    if (t == 0) bb[NBINS] = NE;
    if (t == 0 && u == 0) { off_su[NN] = NE; off_sv[NN] = NE; }
}

// ---------------- scanB: per-bin prefix over blocks, IN PLACE in cnt ----------------
__global__ void k_scanB(int* __restrict__ cnt4, const int* __restrict__ binBase) {
    __shared__ int s[NBLK];
    int u = blockIdx.x / NBINS, j = blockIdx.x % NBINS;
    int* cnt = cnt4 + (size_t)u * NBLK * NBINS;
    const int* bb = binBase + u * (NBINS + 1);
    int t = threadIdx.x;
    for (int i = t; i < NBLK; i += 256) s[i] = cnt[(size_t)i * NBINS + j];
    __syncthreads();
    if (t == 0) {
        int acc = bb[j];
        for (int i = 0; i < NBLK; i++) { int v = s[i]; s[i] = acc; acc += v; }
    }
    __syncthreads();
    for (int i = t; i < NBLK; i += 256) cnt[(size_t)i * NBINS + j] = s[i];
}

// ---------------- p3: dual scatter into bin order (coalesced cursor loads) ----------------
__global__ __launch_bounds__(256) void k_p3(const int* __restrict__ src,
                                            const int* __restrict__ dst,
                                            const int* __restrict__ cntD,
                                            const int* __restrict__ cntS,
                                            int2* __restrict__ sortedD,
                                            int* __restrict__ sortedS) {
    __shared__ int curD[NBINS], curS[NBINS];
    int t = threadIdx.x, b = blockIdx.x;
    for (int i = t; i < NBINS; i += 256) {
        curD[i] = cntD[(size_t)b * NBINS + i];
        curS[i] = cntS[(size_t)b * NBINS + i];
    }
    __syncthreads();
    int base = b * EPB;
#pragma unroll
    for (int i = 0; i < EPB / 1024; i++) {
        int idx = base + i * 1024 + t * 4;
        if (idx < NE) {
            int4 s4 = *(const int4*)(src + idx);
            int4 d4 = *(const int4*)(dst + idx);
            int p;
            p = atomicAdd(&curD[d4.x >> 7], 1); sortedD[p] = make_int2(s4.x, d4.x);
            p = atomicAdd(&curD[d4.y >> 7], 1); sortedD[p] = make_int2(s4.y, d4.y);
            p = atomicAdd(&curD[d4.z >> 7], 1); sortedD[p] = make_int2(s4.z, d4.z);
            p = atomicAdd(&curD[d4.w >> 7], 1); sortedD[p] = make_int2(s4.w, d4.w);
            p = atomicAdd(&curS[s4.x >> 7], 1); sortedS[p] = s4.x;
            p = atomicAdd(&curS[s4.y >> 7], 1); sortedS[p] = s4.y;
            p = atomicAdd(&curS[s4.z >> 7], 1); sortedS[p] = s4.z;
            p = atomicAdd(&curS[s4.w >> 7], 1); sortedS[p] = s4.w;
        }
    }
}

// ---------------- p4 merged: [0,NBINS) counting-sort -> CSR; [NBINS,2N) src-hist ----------------
__global__ __launch_bounds__(256) void k_p4(const int2* __restrict__ sortedD,
                                            const int* __restrict__ sortedS,
                                            const int* __restrict__ bbD,
                                            const int* __restrict__ bbS,
                                            int* __restrict__ off,
                                            int* __restrict__ edges,
                                            int* __restrict__ cnt_src) {
    __shared__ int hist[BINW], pre[BINW], cur[BINW];
    int t = threadIdx.x;
    if (blockIdx.x < NBINS) {
        int bin = blockIdx.x;
        if (t < BINW) hist[t] = 0;
        __syncthreads();
        int e0 = bbD[bin], e1 = bbD[bin + 1];
        for (int e = e0 + t; e < e1; e += 256)
            atomicAdd(&hist[sortedD[e].y & (BINW - 1)], 1);
        __syncthreads();
        if (t == 0) {
            int a = 0;
            for (int i = 0; i < BINW; i++) { pre[i] = a; a += hist[i]; }
        }
        __syncthreads();
        if (t < BINW) {
            cur[t] = pre[t];
            int node = bin * BINW + t;
            if (node < NN) off[node] = e0 + pre[t];
        }
        __syncthreads();
        for (int e = e0 + t; e < e1; e += 256) {
            int2 ed = sortedD[e];
            int p = atomicAdd(&cur[ed.y & (BINW - 1)], 1);
            edges[e0 + p] = ed.x;
        }
    } else {
        int bin = blockIdx.x - NBINS;
        if (t < BINW) hist[t] = 0;
        __syncthreads();
        int e0 = bbS[bin], e1 = bbS[bin + 1];
        for (int e = e0 + t; e < e1; e += 256)
            atomicAdd(&hist[sortedS[e] & (BINW - 1)], 1);
        __syncthreads();
        if (t < BINW) {
            int node = bin * BINW + t;
            if (node < NN) cnt_src[node] = hist[t];
        }
    }
}

// ---------------- t1: y = (x*sn)@W1 (bf16) ----------------
__global__ __launch_bounds__(256) void k_t1(const float* __restrict__ x,
                                            const float* __restrict__ W1,
                                            const int* __restrict__ cnt_src,
                                            ushort_t* __restrict__ y) {
    __shared__ float sW[2048];
    __shared__ float sx[8 * 65];
    int t = threadIdx.x;
    int node0 = blockIdx.x * 8;
    for (int i = t; i < 2048; i += 256) sW[i] = W1[i];
    for (int i = t; i < 512; i += 256) {
        int r = i >> 6, k = i & 63;
        sx[r * 65 + k] = x[(size_t)(node0 + r) * 64 + k];
    }
    __syncthreads();
    int r = t >> 5, c = t & 31;
    int node = node0 + r;
    float sn = rsqrtf(fmaxf((float)cnt_src[node], 1.0f));
    float acc = 0.0f;
#pragma unroll
    for (int k = 0; k < 64; k++) acc += sx[r * 65 + k] * sW[k * 32 + c];
    acc *= sn;   // row scalar commutes with @W1
    y[(size_t)node * 32 + c] = (ushort_t)f2bf(acc);
}

// ---------------- t2: y2 = (HTb_rows(0..31)*sn)@W2 (bf16 in, bf16 out) ----------------
__global__ __launch_bounds__(256) void k_t2(const ushort_t* __restrict__ HTb,
                                            const float* __restrict__ W2,
                                            const int* __restrict__ cnt_src,
                                            ushort_t* __restrict__ y2) {
    __shared__ float sW[512];
    __shared__ float sx[16 * 33];
    int t = threadIdx.x;
    int node0 = blockIdx.x * 16;
    for (int i = t; i < 512; i += 256) sW[i] = W2[i];
    for (int i = t; i < 512; i += 256) {
        int r = i & 15, k = i >> 4;  // r fast -> coalesced over node dim
        sx[r * 33 + k] = bf2f(HTb[(size_t)k * NN + node0 + r]);
    }
    __syncthreads();
    int r = t >> 4, c = t & 15;
    int node = node0 + r;
    float sn = rsqrtf(fmaxf((float)cnt_src[node], 1.0f));
    float acc = 0.0f;
#pragma unroll
    for (int k = 0; k < 32; k++) acc += sx[r * 33 + k] * sW[k * 16 + c];
    acc *= sn;
    y2[(size_t)node * 16 + c] = (ushort_t)f2bf(acc);
}

// ---------------- CSR gather aggregation, packed-uint y, bf16 HTb output ----------------
template <int F, int RELU>
__global__ __launch_bounds__(256) void k_agg(
        const uint_t* __restrict__ y, const int* __restrict__ off,
        const int* __restrict__ edges, const float* __restrict__ bias,
        ushort_t* __restrict__ HTb, int coloff) {
    constexpr int L = F / 2;
    constexpr int NPB = 256 / L;
    int t = threadIdx.x;
    int g = t / L, c2 = t % L;
    int node = blockIdx.x * NPB + g;
    int e0 = off[node], e1 = off[node + 1];
    int deg = e1 - e0;
    const int* srow = edges + e0;
    float a0 = 0.0f, a1 = 0.0f;
    int e = 0;
    for (; e + 3 < deg; e += 4) {
        int s0 = srow[e], s1 = srow[e + 1], s2 = srow[e + 2], s3 = srow[e + 3];
        uint_t u0 = y[(size_t)s0 * L + c2];
        uint_t u1 = y[(size_t)s1 * L + c2];
        uint_t u2 = y[(size_t)s2 * L + c2];
        uint_t u3 = y[(size_t)s3 * L + c2];
        a0 += __uint_as_float(u0 << 16) + __uint_as_float(u1 << 16)
            + __uint_as_float(u2 << 16) + __uint_as_float(u3 << 16);
        a1 += __uint_as_float(u0 & 0xFFFF0000u) + __uint_as_float(u1 & 0xFFFF0000u)
            + __uint_as_float(u2 & 0xFFFF0000u) + __uint_as_float(u3 & 0xFFFF0000u);
    }
    for (; e < deg; e++) {
        uint_t u = y[(size_t)srow[e] * L + c2];
        a0 += __uint_as_float(u << 16);
        a1 += __uint_as_float(u & 0xFFFF0000u);
    }
    float dn = rsqrtf(fmaxf((float)deg, 1.0f));
    float v0 = a0 * dn + bias[2 * c2];
    float v1 = a1 * dn + bias[2 * c2 + 1];
    if (RELU) { v0 = fmaxf(v0, 0.0f); v1 = fmaxf(v1, 0.0f); }
    HTb[(size_t)(coloff + 2 * c2) * NN + node] = (ushort_t)f2bf(v0);
    HTb[(size_t)(coloff + 2 * c2 + 1) * NN + node] = (ushort_t)f2bf(v1);
}

// ---------------- pooling v9: MFMA bf16 GEMM, direct-global fragments ----------------
// pool8's ceiling was structural: fp32-FMA formulation needs 64KB LDS read + 768 FMA-cyc
// per block-step (LDS BW == VALU co-bottleneck, VALUBusy capped ~45%). Reformulate as
// mfma_f32_16x16x32_bf16: wave tile 16 graphs x 16 cols; A = len (fp32 read, cvt->bf16
// in-reg), B = HTb (bf16, 16B/lane contiguous). No LDS staging, no per-step barriers.
// Block 384thr = 6 waves = 3 col-tiles x 2 k-partners (even/odd 64-k tiles); one
// end-of-kernel LDS reduce pairs the k-partners; 393K atomics into pooled.
// Frag layouts (guide §3, m89-verified C/D): A lane l -> row l&15, k=(l>>4)*8+i;
// B lane l -> col l&15, k=(l>>4)*8+i; C/D lane l reg r -> row (l>>4)*4+r, col l&15.
__global__ __launch_bounds__(384) void k_pool9(
        const float* __restrict__ lenA, const float* __restrict__ lenB,
        const ushort_t* __restrict__ HTbA, const ushort_t* __restrict__ HTbB,
        float* __restrict__ pooled) {
    __shared__ float red[3][256][4];
    const int mat = blockIdx.z;
    const float* __restrict__ len = mat ? lenB : lenA;
    const ushort_t* __restrict__ HTb = mat ? HTbB : HTbA;
    const int colbase = mat ? 48 : 0;
    const int b0 = blockIdx.x * 16;
    const int w = threadIdx.x >> 6;   // 0..5
    const int l = threadIdx.x & 63;
    const int c = w >> 1;             // col tile 0..2
    const int kh = w & 1;             // k-partner
    const int rc = l & 15;
    const int seg = l >> 4;           // 0..3

    const int kc0 = blockIdx.y * PK;
    const float* lrow = len + (size_t)(b0 + rc) * NN;          // A row (graph b0+rc)
    const ushort_t* hrow = HTb + (size_t)(c * 16 + rc) * NN;   // B col (HTb row)

    f32x4v acc = {0.0f, 0.0f, 0.0f, 0.0f};

#pragma unroll 2
    for (int tstep = 0; tstep < PK / 128; tstep++) {
        int k0 = kc0 + (2 * tstep + kh) * 64;
#pragma unroll
        for (int h = 0; h < 2; h++) {
            int kb = k0 + h * 32 + seg * 8;   // 8|NN and 8|kb -> segment never straddles NN
            short8v a, b;
            if (kb < NN) {
                f32x4v a0 = *(const f32x4v*)(lrow + kb);
                f32x4v a1 = *(const f32x4v*)(lrow + kb + 4);
                a[0] = f2bf(a0.x); a[1] = f2bf(a0.y); a[2] = f2bf(a0.z); a[3] = f2bf(a0.w);
                a[4] = f2bf(a1.x); a[5] = f2bf(a1.y); a[6] = f2bf(a1.z); a[7] = f2bf(a1.w);
                b = *(const short8v*)(hrow + kb);
            } else {
                a = (short8v)0;
                b = (short8v)0;
            }
            acc = __builtin_amdgcn_mfma_f32_16x16x32_bf16(a, b, acc, 0, 0, 0);
        }
    }

    if (kh == 1) {
        *(f32x4v*)&red[c][l][0] = acc;
    }
    __syncthreads();
    if (kh == 0) {
        f32x4v o = *(const f32x4v*)&red[c][l][0];
#pragma unroll
        for (int r = 0; r < 4; r++) {
            float v = acc[r] + o[r];
            atomicAdd(&pooled[(b0 + seg * 4 + r) * 96 + colbase + c * 16 + rc], v);
        }
    }
}

// ---------------- MLP head ----------------
__global__ void k_mlp(const float* __restrict__ pooled,
                      const float* __restrict__ fc1w, const float* __restrict__ fc1b,
                      const float* __restrict__ fc2w, const float* __restrict__ fc2b,
                      const float* __restrict__ fc3w, const float* __restrict__ fc3b,
                      float* __restrict__ out) {
    __shared__ float srow[96];
    __shared__ float sh[64];
    __shared__ float sh2[16];
    int b = blockIdx.x, t = threadIdx.x; // 64 threads
    srow[t] = pooled[b * 96 + t];
    if (t < 32) srow[64 + t] = pooled[b * 96 + 64 + t];
    __syncthreads();
    float acc = fc1b[t];
    for (int k = 0; k < 96; k++) acc += srow[k] * fc1w[k * 64 + t];
    sh[t] = fmaxf(acc, 0.0f);
    __syncthreads();
    if (t < 16) {
        float a2 = fc2b[t];
        for (int k = 0; k < 64; k++) a2 += sh[k] * fc2w[k * 16 + t];
        sh2[t] = fmaxf(a2, 0.0f);
    }
    __syncthreads();
    if (t == 0) {
        float a3 = fc3b[0];
        for (int k = 0; k < 16; k++) a3 += sh2[k] * fc3w[k];
        out[b] = a3;
    }
}

extern "C" void kernel_launch(void* const* d_in, const int* in_sizes, int n_in,
                              void* d_out, int out_size, void* d_ws, size_t ws_size,
                              hipStream_t stream) {
    const float* solute_x  = (const float*)d_in[0];
    const float* solvent_x = (const float*)d_in[1];
    const float* su_len    = (const float*)d_in[2];
    const float* sv_len    = (const float*)d_in[3];
    const int*   su_src    = (const int*)d_in[4];
    const int*   su_dst    = (const int*)d_in[5];
    const int*   sv_src    = (const int*)d_in[6];
    const int*   sv_dst    = (const int*)d_in[7];
    const float* W1  = (const float*)d_in[8];
    const float* b1  = (const float*)d_in[9];
    const float* W2  = (const float*)d_in[10];
    const float* b2  = (const float*)d_in[11];
    const float* fc1w = (const float*)d_in[12];
    const float* fc1b = (const float*)d_in[13];
    const float* fc2w = (const float*)d_in[14];
    const float* fc2b = (const float*)d_in[15];
    const float* fc3w = (const float*)d_in[16];
    const float* fc3b = (const float*)d_in[17];
    float* out = (float*)d_out;

    // ---- arena (4B words), total ~70.8 MB ----
    char* ws = (char*)d_ws;
    size_t o = 0;
    auto alloc = [&](size_t elems) { void* p = ws + o * 4; o += elems; return p; };
    int* cnt4     = (int*)alloc((size_t)4 * NBLK * NBINS);  // [D_su][S_su][D_sv][S_sv]
    int* binTot   = (int*)alloc(4 * NBINS);
    int* binBase  = (int*)alloc(4 * (NBINS + 1));
    int* off_su   = (int*)alloc(NN + 1);
    int* off_sv   = (int*)alloc(NN + 1);
    int* csrc_su  = (int*)alloc(NN);
    int* csrc_sv  = (int*)alloc(NN);
    float* pooled = (float*)alloc(NB * 96);
    int* edges_su = (int*)alloc(NE);
    int* edges_sv = (int*)alloc(NE);
    o = (o + 1) & ~(size_t)1;                 // 8B align for int2
    // union region X: build {sortedD int2 NE = 25.6MB, sortedS int NE = 12.8MB} = 38.4MB
    //                 compute {ybuf 6.4MB + HTb_su 9.6MB + HTb_sv 9.6MB} = 25.6MB
    char* X = ws + o * 4;
    int2*     sortedD = (int2*)X;
    int*      sortedS = (int*)(X + (size_t)NE * 8);
    uint_t*   ybuf    = (uint_t*)X;
    ushort_t* HTb_su  = (ushort_t*)(X + (size_t)NN * 64);
    ushort_t* HTb_sv  = (ushort_t*)(X + (size_t)NN * 160);

    hipMemsetAsync(binTot, 0, 4 * NBINS * 4, stream);
    hipMemsetAsync(pooled, 0, NB * 96 * 4, stream);

    // ==== phase 1: histograms + scans for BOTH graphs in merged launches ====
    k_p1<<<2 * NBLK, 256, 0, stream>>>(su_src, su_dst, sv_src, sv_dst, cnt4, binTot);
    k_scanA<<<4, 256, 0, stream>>>(binTot, binBase, off_su, off_sv);
    k_scanB<<<4 * NBINS, 256, 0, stream>>>(cnt4, binBase);

    const int* g_src[2]  = {su_src, sv_src};
    const int* g_dst[2]  = {su_dst, sv_dst};
    int* g_off[2]        = {off_su, off_sv};
    int* g_edges[2]      = {edges_su, edges_sv};
    int* g_csrc[2]       = {csrc_su, csrc_sv};

    // per-graph: scatter + counting-sort (sorted buffers reused sequentially)
    for (int g = 0; g < 2; g++) {
        const int* cntD = cnt4 + (size_t)(2 * g) * NBLK * NBINS;
        const int* cntS = cnt4 + (size_t)(2 * g + 1) * NBLK * NBINS;
        const int* bbD  = binBase + (2 * g) * (NBINS + 1);
        const int* bbS  = binBase + (2 * g + 1) * (NBINS + 1);
        k_p3<<<NBLK, 256, 0, stream>>>(g_src[g], g_dst[g], cntD, cntS, sortedD, sortedS);
        k_p4<<<2 * NBINS, 256, 0, stream>>>(sortedD, sortedS, bbD, bbS,
                                            g_off[g], g_edges[g], g_csrc[g]);
    }

    // ==== phase 2: GCN layers (sorted buffers dead; ybuf/HTb take over region X) ====
    const float* g_x[2]  = {solute_x, solvent_x};
    ushort_t* g_HTb[2]   = {HTb_su, HTb_sv};
    for (int g = 0; g < 2; g++) {
        k_t1<<<NN / 8, 256, 0, stream>>>(g_x[g], W1, g_csrc[g], (ushort_t*)ybuf);
        k_agg<32, 1><<<NN / 16, 256, 0, stream>>>(ybuf, g_off[g], g_edges[g], b1, g_HTb[g], 0);
        k_t2<<<NN / 16, 256, 0, stream>>>(g_HTb[g], W2, g_csrc[g], (ushort_t*)ybuf);
        k_agg<16, 0><<<NN / 32, 256, 0, stream>>>(ybuf, g_off[g], g_edges[g], b2, g_HTb[g], 32);
    }

    // ==== pooling (MFMA) + MLP ====
    {
        dim3 gr(NB / 16, PNK, 2);
        k_pool9<<<gr, 384, 0, stream>>>(su_len, sv_len, HTb_su, HTb_sv, pooled);
    }
    k_mlp<<<NB, 64, 0, stream>>>(pooled, fc1w, fc1b, fc2w, fc2b, fc3w, fc3b, out);
}